// Round 1
// 570.226 us; speedup vs baseline: 1.0108x; 1.0108x over previous
//
#include <hip/hip_runtime.h>

#define N_NODES 100000
#define N_EDGES 1600000
#define IN_DIM 128
#define HID 256
#define N_CLS 32
#define BN_EPS 1e-5f

#define SCAN_CHUNK 1024
#define SCAN_NB ((N_NODES + SCAN_CHUNK - 1) / SCAN_CHUNK)   // 98
#define GEMM_NBY ((N_NODES + 127) / 128)                    // 782
#define GEMM_NB (GEMM_NBY * 2)                              // 1564 blocks (2 n-tiles)

// ---- bucketed CSR fill parameters ----
#define NBUCK 16
#define BUCK_NODES 6250        // 16 * 6250 = 100000 exactly
#define BUCK_CAP 112000        // expected 100K/bucket, sd ~306 -> huge margin
#define PASSA_CHUNK 4096       // edges staged per block (32 KB LDS)
#define PASSA_NB ((N_EDGES + PASSA_CHUNK - 1) / PASSA_CHUNK)  // 391
#define FILL_SUBS 64           // blocks per bucket in pass B

typedef unsigned short bf16;
typedef __attribute__((ext_vector_type(8))) short short8;
typedef __attribute__((ext_vector_type(4))) float float4v;
typedef __attribute__((ext_vector_type(2))) float floatx2;

__device__ __forceinline__ float bf2f(bf16 h) {
    return __uint_as_float(((unsigned int)h) << 16);
}
__device__ __forceinline__ bf16 f2bf(float f) {
    unsigned int u = __float_as_uint(f);
    u += 0x7FFFu + ((u >> 16) & 1u);   // round-to-nearest-even
    return (bf16)(u >> 16);
}
__device__ __forceinline__ float blo(unsigned int u) { return __uint_as_float(u << 16); }
__device__ __forceinline__ float bhi(unsigned int u) { return __uint_as_float(u & 0xFFFF0000u); }
__device__ __forceinline__ unsigned int pack2(float lo, float hi) {
    return (unsigned int)f2bf(lo) | ((unsigned int)f2bf(hi) << 16);
}

// fp8 (OCP e4m3 on gfx950) hardware conversions
__device__ __forceinline__ void acc8_fp8(uint2 w, float* a) {
    floatx2 f0 = __builtin_amdgcn_cvt_pk_f32_fp8(w.x, false);
    floatx2 f1 = __builtin_amdgcn_cvt_pk_f32_fp8(w.x, true);
    floatx2 f2 = __builtin_amdgcn_cvt_pk_f32_fp8(w.y, false);
    floatx2 f3 = __builtin_amdgcn_cvt_pk_f32_fp8(w.y, true);
    a[0] += f0.x; a[1] += f0.y; a[2] += f1.x; a[3] += f1.y;
    a[4] += f2.x; a[5] += f2.y; a[6] += f3.x; a[7] += f3.y;
}
__device__ __forceinline__ unsigned int pack4_fp8(float a, float b, float c, float d) {
    int p = 0;
    p = __builtin_amdgcn_cvt_pk_fp8_f32(a, b, p, false);
    p = __builtin_amdgcn_cvt_pk_fp8_f32(c, d, p, true);
    return (unsigned int)p;
}

// ---------------- CSR build: pass A — bucket scatter + degree histogram ----------------
// Streams edges once. Per block: LDS-stage 4096 (src,dst) pairs grouped by dst-bucket,
// reserve per-bucket global ranges with one atomic per bucket, write contiguous runs
// (~2 KB avg per bucket per block -> near-streaming HBM writes, no line amplification).
// Also folds in the per-node degree histogram (was hist_kernel).

__global__ __launch_bounds__(256) void bucket_scatter_kernel(
    const int* __restrict__ esrc, const int* __restrict__ edst,
    int* __restrict__ counts, int* __restrict__ bcur, int2* __restrict__ bstore) {
    __shared__ int lhist[NBUCK], lbase[NBUCK], gbase[NBUCK], lcur[NBUCK];
    __shared__ int2 stage[PASSA_CHUNK];    // 32 KB
    const int tid = threadIdx.x;
    if (tid < NBUCK) lhist[tid] = 0;
    __syncthreads();

    const int base = blockIdx.x * PASSA_CHUNK;
    const int nedge = min(PASSA_CHUNK, N_EDGES - base);
    // N_EDGES % 16 == 0, so each thread's 16-edge chunk is all-or-nothing.
    const bool act = (tid * 16) < nedge;
    int s[16], d[16], bk[16];
    if (act) {
        const int4* s4 = (const int4*)(esrc + base + tid * 16);
        const int4* d4 = (const int4*)(edst + base + tid * 16);
#pragma unroll
        for (int t = 0; t < 4; ++t) {
            int4 sv = s4[t], dv = d4[t];
            s[t * 4 + 0] = sv.x; s[t * 4 + 1] = sv.y; s[t * 4 + 2] = sv.z; s[t * 4 + 3] = sv.w;
            d[t * 4 + 0] = dv.x; d[t * 4 + 1] = dv.y; d[t * 4 + 2] = dv.z; d[t * 4 + 3] = dv.w;
        }
#pragma unroll
        for (int u = 0; u < 16; ++u) {
            bk[u] = (int)((unsigned)d[u] / BUCK_NODES);
            atomicAdd(&counts[d[u]], 1);        // degree histogram (global)
            atomicAdd(&lhist[bk[u]], 1);        // block-local bucket counts (LDS)
        }
    }
    __syncthreads();
    if (tid == 0) {
        int run = 0;
#pragma unroll
        for (int b = 0; b < NBUCK; ++b) { lbase[b] = run; lcur[b] = run; run += lhist[b]; }
    }
    if (tid < NBUCK) gbase[tid] = atomicAdd(&bcur[tid], lhist[tid]);
    __syncthreads();
    if (act) {
#pragma unroll
        for (int u = 0; u < 16; ++u) {
            int p = atomicAdd(&lcur[bk[u]], 1);
            stage[p] = make_int2(s[u], d[u]);
        }
    }
    __syncthreads();
    // write out: LDS position p -> global bstore[b*CAP + gbase[b] + (p - lbase[b])]
    for (int p = tid; p < nedge; p += 256) {
        int2 e = stage[p];
        int b = (int)((unsigned)e.y / BUCK_NODES);
        int gp = gbase[b] + (p - lbase[b]);
        if (gp < BUCK_CAP) bstore[(size_t)b * BUCK_CAP + gp] = e;
    }
}

// ---------------- CSR build: pass B — per-bucket fine scatter ----------------
// Each bucket's csr window is ~400 KB; bucket = blockIdx & 15 puts all of a bucket's
// blocks on one XCD (round-robin heuristic) so the window is L2-resident and random
// 4B writes combine into full-line evictions.

__global__ __launch_bounds__(256) void fill_bucket_kernel(
    const int2* __restrict__ bstore, const int* __restrict__ bcnt,
    const int* __restrict__ off, int* __restrict__ cursor, int* __restrict__ csr) {
    const int bk = blockIdx.x & (NBUCK - 1);
    const int sub = blockIdx.x >> 4;
    const int n = bcnt[bk];
    const int2* ep = bstore + (size_t)bk * BUCK_CAP;
    for (int i = sub * 256 + threadIdx.x; i < n; i += 256 * FILL_SUBS) {
        int2 e = ep[i];
        int p = atomicAdd(&cursor[e.y], 1);
        csr[off[e.y] + p] = e.x;
    }
}

// ---------------- prefix scans (unchanged) ----------------

__global__ void scan1_kernel(const int* __restrict__ counts, int* __restrict__ bsums) {
    __shared__ int wsum[4];
    int base = blockIdx.x * SCAN_CHUNK + threadIdx.x * 4;
    int s = 0;
    if (base + 4 <= N_NODES) {
        int4 v = *(const int4*)(counts + base);
        s = v.x + v.y + v.z + v.w;
    } else {
        for (int j = 0; j < 4; ++j) if (base + j < N_NODES) s += counts[base + j];
    }
    for (int d = 32; d > 0; d >>= 1) s += __shfl_down(s, d, 64);
    if ((threadIdx.x & 63) == 0) wsum[threadIdx.x >> 6] = s;
    __syncthreads();
    if (threadIdx.x == 0) bsums[blockIdx.x] = wsum[0] + wsum[1] + wsum[2] + wsum[3];
}

__global__ void scan2_kernel(const int* __restrict__ bsums, int* __restrict__ boffs) {
    __shared__ int sh[128];
    int i = threadIdx.x;
    int v = (i < SCAN_NB) ? bsums[i] : 0;
    sh[i] = v;
    __syncthreads();
    for (int d = 1; d < 128; d <<= 1) {
        int t = (i >= d) ? sh[i - d] : 0;
        __syncthreads();
        sh[i] += t;
        __syncthreads();
    }
    if (i < SCAN_NB) boffs[i] = sh[i] - v;
}

__global__ void scan3_kernel(const int* __restrict__ counts, const int* __restrict__ boffs,
                             int* __restrict__ off) {
    __shared__ int sh[256];
    int tid = threadIdx.x;
    int base = blockIdx.x * SCAN_CHUNK + tid * 4;
    int c0 = 0, c1 = 0, c2 = 0, c3 = 0;
    if (base + 4 <= N_NODES) {
        int4 v = *(const int4*)(counts + base);
        c0 = v.x; c1 = v.y; c2 = v.z; c3 = v.w;
    } else {
        if (base + 0 < N_NODES) c0 = counts[base + 0];
        if (base + 1 < N_NODES) c1 = counts[base + 1];
        if (base + 2 < N_NODES) c2 = counts[base + 2];
        if (base + 3 < N_NODES) c3 = counts[base + 3];
    }
    int ts = c0 + c1 + c2 + c3;
    sh[tid] = ts;
    __syncthreads();
    for (int d = 1; d < 256; d <<= 1) {
        int t = (tid >= d) ? sh[tid - d] : 0;
        __syncthreads();
        sh[tid] += t;
        __syncthreads();
    }
    int run = boffs[blockIdx.x] + sh[tid] - ts;
    if (base + 0 < N_NODES) off[base + 0] = run; run += c0;
    if (base + 1 < N_NODES) off[base + 1] = run; run += c1;
    if (base + 2 < N_NODES) off[base + 2] = run; run += c2;
    if (base + 3 < N_NODES) off[base + 3] = run;
    if (blockIdx.x == 0 && tid == 0) off[N_NODES] = N_EDGES;
}

// ---------------- x fp32 -> bf16 + fp8 ----------------

__global__ void convert_x_kernel(const float* __restrict__ x, bf16* __restrict__ xb,
                                 unsigned char* __restrict__ xf8) {
    int i = blockIdx.x * blockDim.x + threadIdx.x;
    int total4 = N_NODES * IN_DIM / 4;
    if (i >= total4) return;
    float4 v = ((const float4*)x)[i];
    ushort4 r;
    r.x = f2bf(v.x); r.y = f2bf(v.y); r.z = f2bf(v.z); r.w = f2bf(v.w);
    ((ushort4*)xb)[i] = r;
    ((unsigned int*)xf8)[i] = pack4_fp8(v.x, v.y, v.z, v.w);
}

// ---------------- combined weight prep ----------------

__global__ void prep_weights_kernel(const float* __restrict__ W1l, const float* __restrict__ W1r,
                                    const float* __restrict__ W2l, const float* __restrict__ W2r,
                                    const float* __restrict__ Wfc,
                                    bf16* __restrict__ w1lt, bf16* __restrict__ w1rt,
                                    bf16* __restrict__ w2lt, bf16* __restrict__ w2rt,
                                    bf16* __restrict__ wfct) {
    const int S1 = IN_DIM * HID;   // 32768
    const int S2 = HID * HID;      // 65536
    const int S3 = HID * N_CLS;    // 8192
    int i = blockIdx.x * blockDim.x + threadIdx.x;
    if (i < 2 * S1 + 2 * S2) {
        const float* W; bf16* Wt; int K, idx;
        if (i < S1)          { W = W1l; Wt = w1lt; K = IN_DIM; idx = i; }
        else if (i < 2 * S1) { W = W1r; Wt = w1rt; K = IN_DIM; idx = i - S1; }
        else if (i < 2 * S1 + S2) { W = W2l; Wt = w2lt; K = HID; idx = i - 2 * S1; }
        else                 { W = W2r; Wt = w2rt; K = HID; idx = i - 2 * S1 - S2; }
        int k = idx / HID, n = idx - k * HID;
        Wt[(size_t)n * K + k] = f2bf(W[idx]);
    } else if (i < 2 * S1 + 2 * S2 + S3) {
        int idx = i - 2 * S1 - 2 * S2;       // idx = k*32 + n
        int k = idx >> 5, n = idx & 31;
        wfct[(size_t)n * HID + k] = f2bf(Wfc[idx]);
    }
}

// ---------------- mean aggregation (fp8 gathers, sub-wave per node, x4 unroll) ----------------

__global__ void aggregate1_kernel(const unsigned char* __restrict__ xf8, const int* __restrict__ off,
                                  const int* __restrict__ csr, bf16* __restrict__ out) {
    int t = blockIdx.x * blockDim.x + threadIdx.x;
    int node = t >> 4;
    int sl = t & 15;
    if (node >= N_NODES) return;
    int s = off[node], e = off[node + 1];
    float inv = 1.0f / (float)max(e - s, 1);
    const uint2* f = (const uint2*)xf8;   // row = 16 uint2
    float a[8] = {0.f, 0.f, 0.f, 0.f, 0.f, 0.f, 0.f, 0.f};
    int i = s;
    for (; i + 4 <= e; i += 4) {
        int u0 = csr[i], u1 = csr[i + 1], u2 = csr[i + 2], u3 = csr[i + 3];
        uint2 w0 = f[(size_t)u0 * 16 + sl];
        uint2 w1 = f[(size_t)u1 * 16 + sl];
        uint2 w2 = f[(size_t)u2 * 16 + sl];
        uint2 w3 = f[(size_t)u3 * 16 + sl];
        acc8_fp8(w0, a); acc8_fp8(w1, a); acc8_fp8(w2, a); acc8_fp8(w3, a);
    }
    for (; i < e; ++i) {
        uint2 w = f[(size_t)csr[i] * 16 + sl];
        acc8_fp8(w, a);
    }
    uint4 r;
    r.x = pack2(a[0] * inv, a[1] * inv);
    r.y = pack2(a[2] * inv, a[3] * inv);
    r.z = pack2(a[4] * inv, a[5] * inv);
    r.w = pack2(a[6] * inv, a[7] * inv);
    ((uint4*)out)[(size_t)node * 16 + sl] = r;
}

__global__ void aggregate2_kernel(const unsigned char* __restrict__ hf8, const int* __restrict__ off,
                                  const int* __restrict__ csr, bf16* __restrict__ out) {
    int t = blockIdx.x * blockDim.x + threadIdx.x;
    int node = t >> 5;
    int sl = t & 31;
    if (node >= N_NODES) return;
    int s = off[node], e = off[node + 1];
    float inv = 1.0f / (float)max(e - s, 1);
    const uint2* f = (const uint2*)hf8;   // row = 32 uint2
    float a[8] = {0.f, 0.f, 0.f, 0.f, 0.f, 0.f, 0.f, 0.f};
    int i = s;
    for (; i + 4 <= e; i += 4) {
        int u0 = csr[i], u1 = csr[i + 1], u2 = csr[i + 2], u3 = csr[i + 3];
        uint2 w0 = f[(size_t)u0 * 32 + sl];
        uint2 w1 = f[(size_t)u1 * 32 + sl];
        uint2 w2 = f[(size_t)u2 * 32 + sl];
        uint2 w3 = f[(size_t)u3 * 32 + sl];
        acc8_fp8(w0, a); acc8_fp8(w1, a); acc8_fp8(w2, a); acc8_fp8(w3, a);
    }
    for (; i < e; ++i) {
        uint2 w = f[(size_t)csr[i] * 32 + sl];
        acc8_fp8(w, a);
    }
    uint4 r;
    r.x = pack2(a[0] * inv, a[1] * inv);
    r.y = pack2(a[2] * inv, a[3] * inv);
    r.z = pack2(a[4] * inv, a[5] * inv);
    r.w = pack2(a[6] * inv, a[7] * inv);
    ((uint4*)out)[(size_t)node * 32 + sl] = r;
}

// ---------------- MFMA dual GEMM (r9 K-loop, compiler-scheduled) + LDS write-combine epilogue ----------------

#define LSTRIDE 40  // 32 + 8 pad (bf16): 80 B rows, 16B-aligned everywhere

template <typename T>
__device__ __forceinline__ void gemm_pass_mfma(
    const T* __restrict__ Ap, const bf16* __restrict__ Wp, int K,
    int tile_m, int tile_n, int M, int tid,
    bf16* As, bf16* Ws, float4v (*acc)[4]) {
    const int lane = tid & 63;
    const int wave = tid >> 6;
    const int rw = (wave >> 1) * 64;
    const int cw = (wave & 1) * 64;
    const int lrow = lane & 15;
    const int quad = lane >> 4;

    for (int k0 = 0; k0 < K; k0 += 32) {
#pragma unroll
        for (int c = tid; c < 512; c += 256) {
            int row = c >> 2, seg = c & 3;
            int grow = tile_m + row;
            uint4 va = {0u, 0u, 0u, 0u};
            if (grow < M) va = *(const uint4*)(Ap + (size_t)grow * K + k0 + seg * 8);
            *(uint4*)(As + row * LSTRIDE + seg * 8) = va;
            uint4 vw = *(const uint4*)(Wp + (size_t)(tile_n + row) * K + k0 + seg * 8);
            *(uint4*)(Ws + row * LSTRIDE + seg * 8) = vw;
        }
        __syncthreads();
        short8 a[4], b[4];
#pragma unroll
        for (int i = 0; i < 4; ++i)
            a[i] = *(const short8*)(As + (rw + i * 16 + lrow) * LSTRIDE + quad * 8);
#pragma unroll
        for (int j = 0; j < 4; ++j)
            b[j] = *(const short8*)(Ws + (cw + j * 16 + lrow) * LSTRIDE + quad * 8);
#pragma unroll
        for (int i = 0; i < 4; ++i)
#pragma unroll
            for (int j = 0; j < 4; ++j)
                acc[i][j] = __builtin_amdgcn_mfma_f32_16x16x32_bf16(a[i], b[j], acc[i][j], 0, 0, 0);
        __syncthreads();
    }
}

template <typename TB>
__global__ __launch_bounds__(256) void gemm_dual_mfma(
    const bf16* __restrict__ A, const bf16* __restrict__ WtA, int KA,
    const TB* __restrict__ B, const bf16* __restrict__ WtB, int KB,
    const float* __restrict__ bias, bf16* __restrict__ C, int M,
    float* __restrict__ psum, float* __restrict__ psq) {
    __shared__ bf16 As[128 * LSTRIDE];
    __shared__ bf16 Ws[128 * LSTRIDE];
    __shared__ float sred[4][64];
    __shared__ float qred[4][64];
    const int tid = threadIdx.x;
    const int lane = tid & 63;
    const int wave = tid >> 6;
    const int rw = (wave >> 1) * 64;
    const int cw = (wave & 1) * 64;
    const int lrow = lane & 15;
    const int quad = lane >> 4;
    const int tile_m = blockIdx.y * 128;
    const int tile_n = blockIdx.x * 128;

    float4v acc[4][4];
#pragma unroll
    for (int i = 0; i < 4; ++i)
#pragma unroll
        for (int j = 0; j < 4; ++j) acc[i][j] = (float4v){0.f, 0.f, 0.f, 0.f};

    gemm_pass_mfma(A, WtA, KA, tile_m, tile_n, M, tid, As, Ws, acc);
    gemm_pass_mfma(B, WtB, KB, tile_m, tile_n, M, tid, As, Ws, acc);
    // (K-loop ends with __syncthreads: ds_reads done, As reusable)

    // ---- epilogue: C/D layout col=lane&15, row=quad*4+reg [verified m89] ----
    // Per-wave LDS slice (16x64 bf16 = 2 KB) -> coalesced 16B global stores.
    bf16* slice = As + wave * 1024;
    float bvj[4];
#pragma unroll
    for (int j = 0; j < 4; ++j) bvj[j] = bias[tile_n + cw + j * 16 + lrow];
    float cs[4] = {0.f, 0.f, 0.f, 0.f}, cq[4] = {0.f, 0.f, 0.f, 0.f};

#pragma unroll
    for (int i = 0; i < 4; ++i) {
#pragma unroll
        for (int j = 0; j < 4; ++j) {
#pragma unroll
            for (int r = 0; r < 4; ++r) {
                int row = tile_m + rw + i * 16 + quad * 4 + r;
                float v = acc[i][j][r] + bvj[j];
                if (row < M) { cs[j] += v; cq[j] += v * v; }
                slice[(quad * 4 + r) * 64 + j * 16 + lrow] = f2bf(v);
            }
        }
        __syncthreads();
        // readback: 128 uint4 chunks (16 rows x 8 chunks), lane handles 2
#pragma unroll
        for (int c = 0; c < 2; ++c) {
            int ch = lane + c * 64;
            int lr = ch >> 3, sg = ch & 7;
            int grow = tile_m + rw + i * 16 + lr;
            if (grow < M) {
                uint4 v = *(const uint4*)(slice + lr * 64 + sg * 8);
                *(uint4*)(C + (size_t)grow * HID + tile_n + cw + sg * 8) = v;
            }
        }
        __syncthreads();
    }

    // reduce across the 4 quads that share each (j,lrow) column
#pragma unroll
    for (int j = 0; j < 4; ++j) {
        cs[j] += __shfl_xor(cs[j], 16, 64); cs[j] += __shfl_xor(cs[j], 32, 64);
        cq[j] += __shfl_xor(cq[j], 16, 64); cq[j] += __shfl_xor(cq[j], 32, 64);
    }
    if (quad == 0) {
#pragma unroll
        for (int j = 0; j < 4; ++j) {
            sred[wave][j * 16 + lrow] = cs[j];
            qred[wave][j * 16 + lrow] = cq[j];
        }
    }
    __syncthreads();
    int bid = blockIdx.y * gridDim.x + blockIdx.x;
    if (tid < 128) {
        int grp = tid >> 6, idx = tid & 63;
        psum[(size_t)bid * 128 + tid] = sred[grp][idx] + sred[grp + 2][idx];
    } else {
        int t = tid - 128;
        int grp = t >> 6, idx = t & 63;
        psq[(size_t)bid * 128 + t] = qred[grp][idx] + qred[grp + 2][idx];
    }
}

// reduce per-block partials -> stats[0..255]=sum, stats[256..511]=sumsq
__global__ void bn_finalize_kernel(const float* __restrict__ psum, const float* __restrict__ psq,
                                   float* __restrict__ stats, int nby) {
    const float* src = blockIdx.y ? psq : psum;
    int c = threadIdx.x;           // 0..255 = global column
    int bx = c >> 7, cl = c & 127;
    int per = (nby + gridDim.x - 1) / gridDim.x;
    int b0 = blockIdx.x * per, b1 = min(b0 + per, nby);
    float s = 0.f;
    for (int by = b0; by < b1; ++by) s += src[(size_t)(by * 2 + bx) * 128 + cl];
    atomicAdd(&stats[blockIdx.y * HID + c], s);
}

// ---------------- BN apply + ReLU (layer 1; also emits fp8 copy for gather) ----------------

__global__ void bn_apply_relu_kernel(bf16* __restrict__ h, unsigned char* __restrict__ hf8,
                                     const float* __restrict__ stats,
                                     const float* __restrict__ g, const float* __restrict__ be,
                                     int M) {
    int i4 = blockIdx.x * blockDim.x + threadIdx.x;
    int total4 = M * (HID / 4);
    if (i4 >= total4) return;
    int col4 = i4 & (HID / 4 - 1);
    ushort4 v = ((const ushort4*)h)[i4];
    float invN = 1.0f / (float)M;
    float o[4] = {bf2f(v.x), bf2f(v.y), bf2f(v.z), bf2f(v.w)};
#pragma unroll
    for (int j = 0; j < 4; ++j) {
        int col = col4 * 4 + j;
        float mu = stats[col] * invN;
        float var = stats[HID + col] * invN - mu * mu;
        float sc = rsqrtf(var + BN_EPS) * g[col];
        float val = (o[j] - mu) * sc + be[col];
        o[j] = val > 0.f ? val : 0.f;
    }
    ushort4 r;
    r.x = f2bf(o[0]); r.y = f2bf(o[1]); r.z = f2bf(o[2]); r.w = f2bf(o[3]);
    ((ushort4*)h)[i4] = r;
    ((unsigned int*)hf8)[i4] = pack4_fp8(o[0], o[1], o[2], o[3]);
}

// ---------------- final FC (MFMA) with fused BN2+ReLU ----------------

#define BSTR 264   // 256 + 8 pad

__global__ __launch_bounds__(256) void fc_bn_mfma_kernel(
    const bf16* __restrict__ h, const float* __restrict__ stats,
    const float* __restrict__ g, const float* __restrict__ be,
    const bf16* __restrict__ WfcT, const float* __restrict__ bfc,
    float* __restrict__ out, int M) {
    __shared__ bf16 Bs[32 * BSTR];
    __shared__ float sc_s[HID], sh_s[HID];
    int tid = threadIdx.x;
    for (int i = tid; i < 32 * 32; i += 256) {   // 1024 16B chunks
        int rrow = i >> 5, seg = i & 31;
        *(uint4*)(Bs + rrow * BSTR + seg * 8) = *(const uint4*)(WfcT + (size_t)rrow * HID + seg * 8);
    }
    {
        float invN = 1.0f / (float)M;
        float mu = stats[tid] * invN;
        float var = stats[HID + tid] * invN - mu * mu;
        float s = rsqrtf(var + BN_EPS) * g[tid];
        sc_s[tid] = s;
        sh_s[tid] = be[tid] - mu * s;
    }
    __syncthreads();
    int wave = tid >> 6, lane = tid & 63, lrow = lane & 15, quad = lane >> 4;
    int row = blockIdx.x * 64 + wave * 16 + lrow;
    const bf16* hrow = h + (size_t)row * HID;
    float4v acc0 = {0.f, 0.f, 0.f, 0.f}, acc1 = {0.f, 0.f, 0.f, 0.f};
#pragma unroll
    for (int ks = 0; ks < 8; ++ks) {
        int k0 = ks * 32 + quad * 8;
        uint4 av = {0u, 0u, 0u, 0u};
        if (row < M) av = *(const uint4*)(hrow + k0);
        union { unsigned int u[4]; short8 s8; } cvt;
        unsigned int* avp = (unsigned int*)&av;
#pragma unroll
        for (int t = 0; t < 4; ++t) {
            int k = k0 + t * 2;
            float v0 = blo(avp[t]) * sc_s[k] + sh_s[k];
            float v1 = bhi(avp[t]) * sc_s[k + 1] + sh_s[k + 1];
            v0 = v0 > 0.f ? v0 : 0.f;
            v1 = v1 > 0.f ? v1 : 0.f;
            cvt.u[t] = pack2(v0, v1);
        }
        short8 b0 = *(const short8*)(Bs + lrow * BSTR + k0);
        short8 b1 = *(const short8*)(Bs + (16 + lrow) * BSTR + k0);
        acc0 = __builtin_amdgcn_mfma_f32_16x16x32_bf16(cvt.s8, b0, acc0, 0, 0, 0);
        acc1 = __builtin_amdgcn_mfma_f32_16x16x32_bf16(cvt.s8, b1, acc1, 0, 0, 0);
    }
    int orow = blockIdx.x * 64 + wave * 16 + quad * 4;
    float bv0 = bfc[lrow], bv1 = bfc[16 + lrow];
#pragma unroll
    for (int r = 0; r < 4; ++r) {
        int rr = orow + r;
        if (rr < M) {
            out[(size_t)rr * N_CLS + lrow] = acc0[r] + bv0;
            out[(size_t)rr * N_CLS + 16 + lrow] = acc1[r] + bv1;
        }
    }
}

// ---------------- launch ----------------

extern "C" void kernel_launch(void* const* d_in, const int* in_sizes, int n_in,
                              void* d_out, int out_size, void* d_ws, size_t ws_size,
                              hipStream_t stream) {
    const float* x   = (const float*)d_in[0];
    const int* esrc  = (const int*)d_in[1];
    const int* edst  = (const int*)d_in[2];
    const float* W1l = (const float*)d_in[3];
    const float* b1  = (const float*)d_in[4];
    const float* W1r = (const float*)d_in[5];
    const float* g1  = (const float*)d_in[6];
    const float* be1 = (const float*)d_in[7];
    const float* W2l = (const float*)d_in[8];
    const float* b2  = (const float*)d_in[9];
    const float* W2r = (const float*)d_in[10];
    const float* g2  = (const float*)d_in[11];
    const float* be2 = (const float*)d_in[12];
    const float* Wfc = (const float*)d_in[13];
    const float* bfc = (const float*)d_in[14];
    float* out = (float*)d_out;

    char* ws = (char*)d_ws;
    size_t o = 0;
    auto carve = [&](size_t bytes) {
        char* p = ws + o;
        o = (o + bytes + 255) & ~(size_t)255;
        return p;
    };
    int*   off    = (int*)carve((N_NODES + 1) * sizeof(int));
    int*   cursor = (int*)carve(N_NODES * sizeof(int));
    int*   csr    = (int*)carve(N_EDGES * sizeof(int));
    int*   bsums  = (int*)carve(SCAN_NB * sizeof(int));
    int*   boffs  = (int*)carve(SCAN_NB * sizeof(int));
    int*   bcur   = (int*)carve(NBUCK * sizeof(int));
    float* stats1 = (float*)carve(2 * HID * sizeof(float));
    float* stats2 = (float*)carve(2 * HID * sizeof(float));
    float* psum   = (float*)carve((size_t)GEMM_NB * 128 * sizeof(float));
    float* psq    = (float*)carve((size_t)GEMM_NB * 128 * sizeof(float));
    bf16*  w1lt   = (bf16*)carve((size_t)IN_DIM * HID * sizeof(bf16));
    bf16*  w1rt   = (bf16*)carve((size_t)IN_DIM * HID * sizeof(bf16));
    bf16*  w2lt   = (bf16*)carve((size_t)HID * HID * sizeof(bf16));
    bf16*  w2rt   = (bf16*)carve((size_t)HID * HID * sizeof(bf16));
    bf16*  wfct   = (bf16*)carve((size_t)N_CLS * HID * sizeof(bf16));
    bf16*  agg    = (bf16*)carve((size_t)N_NODES * HID * sizeof(bf16));
    bf16*  h1     = (bf16*)carve((size_t)N_NODES * HID * sizeof(bf16));
    bf16*  h2     = (bf16*)carve((size_t)N_NODES * HID * sizeof(bf16));
    // overlays inside the h2 region (lifetimes stream-ordered disjoint):
    //   xb  = h2[0   : 25.6MB]  bf16 x   — dead after gemm1
    //   xf8 = h2[25.6: 38.4MB]  fp8 x    — dead after aggregate1
    //   h1f8= h2[0   : 25.6MB]  fp8 bn(h1) — written post-gemm1, read by aggregate2,
    //                                        then gemm2 overwrites h2
    bf16*          xb   = h2;
    unsigned char* xf8  = (unsigned char*)h2 + (size_t)N_NODES * IN_DIM * sizeof(bf16);
    unsigned char* h1f8 = (unsigned char*)h2;
    // overlay inside the agg region (dead until aggregate1 writes it):
    //   bstore = 16 buckets x 112K edges x 8B = 14.3 MB < 51.2 MB
    int2*          bstore = (int2*)agg;

    if (o > ws_size) return;  // clean fail instead of fault

    hipMemsetAsync(cursor, 0, N_NODES * sizeof(int), stream);
    hipMemsetAsync(bcur, 0, NBUCK * sizeof(int), stream);
    hipMemsetAsync(stats1, 0, 2 * HID * sizeof(float), stream);
    hipMemsetAsync(stats2, 0, 2 * HID * sizeof(float), stream);

    // CSR build: bucketed two-phase scatter (pass A folds in the degree histogram)
    bucket_scatter_kernel<<<PASSA_NB, 256, 0, stream>>>(esrc, edst, cursor, bcur, bstore);
    scan1_kernel<<<SCAN_NB, 256, 0, stream>>>(cursor, bsums);
    scan2_kernel<<<1, 128, 0, stream>>>(bsums, boffs);
    scan3_kernel<<<SCAN_NB, 256, 0, stream>>>(cursor, boffs, off);
    hipMemsetAsync(cursor, 0, N_NODES * sizeof(int), stream);
    fill_bucket_kernel<<<NBUCK * FILL_SUBS, 256, 0, stream>>>(bstore, bcur, off, cursor, csr);

    // prep: x -> bf16 + fp8, all weights -> bf16 transposed
    convert_x_kernel<<<(N_NODES * IN_DIM / 4 + 255) / 256, 256, 0, stream>>>(x, xb, xf8);
    {
        int total = 2 * IN_DIM * HID + 2 * HID * HID + HID * N_CLS;
        prep_weights_kernel<<<(total + 255) / 256, 256, 0, stream>>>(
            W1l, W1r, W2l, W2r, Wfc, w1lt, w1rt, w2lt, w2rt, wfct);
    }

    const dim3 ggrid(HID / 128, GEMM_NBY);

    // ---- layer 1 ----
    aggregate1_kernel<<<(N_NODES * 16 + 255) / 256, 256, 0, stream>>>(xf8, off, csr, agg);
    gemm_dual_mfma<bf16><<<ggrid, 256, 0, stream>>>(
        agg, w1lt, IN_DIM, xb, w1rt, IN_DIM, b1, h1, N_NODES, psum, psq);
    bn_finalize_kernel<<<dim3(8, 2), 256, 0, stream>>>(psum, psq, stats1, GEMM_NBY);
    {
        int total4 = N_NODES * (HID / 4);
        bn_apply_relu_kernel<<<(total4 + 255) / 256, 256, 0, stream>>>(h1, h1f8, stats1, g1, be1, N_NODES);
    }

    // ---- layer 2 ----
    aggregate2_kernel<<<(N_NODES * 32 + 255) / 256, 256, 0, stream>>>(h1f8, off, csr, agg);
    gemm_dual_mfma<bf16><<<ggrid, 256, 0, stream>>>(
        agg, w2lt, HID, h1, w2rt, HID, b2, h2, N_NODES, psum, psq);
    bn_finalize_kernel<<<dim3(8, 2), 256, 0, stream>>>(psum, psq, stats2, GEMM_NBY);

    // ---- final FC (MFMA) with fused BN2+ReLU ----
    fc_bn_mfma_kernel<<<(N_NODES + 63) / 64, 256, 0, stream>>>(
        h2, stats2, g2, be2, wfct, bfc, out, N_NODES);
}

// Round 2
// 557.173 us; speedup vs baseline: 1.0345x; 1.0234x over previous
//
#include <hip/hip_runtime.h>

#define N_NODES 100000
#define N_EDGES 1600000
#define IN_DIM 128
#define HID 256
#define N_CLS 32
#define BN_EPS 1e-5f

#define SCAN_CHUNK 1024
#define SCAN_NB ((N_NODES + SCAN_CHUNK - 1) / SCAN_CHUNK)   // 98
#define GEMM_NBY ((N_NODES + 127) / 128)                    // 782
#define GEMM_NB (GEMM_NBY * 2)                              // 1564 blocks (2 n-tiles)

// ---- bucketed CSR fill parameters ----
#define NBUCK 16
#define BUCK_NODES 6250        // 16 * 6250 = 100000 exactly
#define BUCK_CAP 112000        // expected 100K/bucket, sd ~306 -> huge margin
#define PASSA_CHUNK 4096       // edges staged per block (32 KB LDS)
#define PASSA_NB ((N_EDGES + PASSA_CHUNK - 1) / PASSA_CHUNK)  // 391
#define FILL_SUBS 64           // blocks per bucket in pass B

typedef unsigned short bf16;
typedef __attribute__((ext_vector_type(8))) short short8;
typedef __attribute__((ext_vector_type(4))) float float4v;
typedef __attribute__((ext_vector_type(2))) float floatx2;

__device__ __forceinline__ float bf2f(bf16 h) {
    return __uint_as_float(((unsigned int)h) << 16);
}
__device__ __forceinline__ bf16 f2bf(float f) {
    unsigned int u = __float_as_uint(f);
    u += 0x7FFFu + ((u >> 16) & 1u);   // round-to-nearest-even
    return (bf16)(u >> 16);
}
__device__ __forceinline__ float blo(unsigned int u) { return __uint_as_float(u << 16); }
__device__ __forceinline__ float bhi(unsigned int u) { return __uint_as_float(u & 0xFFFF0000u); }
__device__ __forceinline__ unsigned int pack2(float lo, float hi) {
    return (unsigned int)f2bf(lo) | ((unsigned int)f2bf(hi) << 16);
}

// fp8 (OCP e4m3 on gfx950) hardware conversions
__device__ __forceinline__ void acc8_fp8(uint2 w, float* a) {
    floatx2 f0 = __builtin_amdgcn_cvt_pk_f32_fp8(w.x, false);
    floatx2 f1 = __builtin_amdgcn_cvt_pk_f32_fp8(w.x, true);
    floatx2 f2 = __builtin_amdgcn_cvt_pk_f32_fp8(w.y, false);
    floatx2 f3 = __builtin_amdgcn_cvt_pk_f32_fp8(w.y, true);
    a[0] += f0.x; a[1] += f0.y; a[2] += f1.x; a[3] += f1.y;
    a[4] += f2.x; a[5] += f2.y; a[6] += f3.x; a[7] += f3.y;
}
__device__ __forceinline__ unsigned int pack4_fp8(float a, float b, float c, float d) {
    int p = 0;
    p = __builtin_amdgcn_cvt_pk_fp8_f32(a, b, p, false);
    p = __builtin_amdgcn_cvt_pk_fp8_f32(c, d, p, true);
    return (unsigned int)p;
}

// async global->LDS, 16B per lane, wave-uniform LDS base + lane*16
__device__ __forceinline__ void gload16(const void* g, void* l) {
    __builtin_amdgcn_global_load_lds(
        (const __attribute__((address_space(1))) void*)g,
        (__attribute__((address_space(3))) void*)l, 16, 0, 0);
}

// ---------------- CSR build: pass A — bucket scatter + degree histogram ----------------

__global__ __launch_bounds__(256) void bucket_scatter_kernel(
    const int* __restrict__ esrc, const int* __restrict__ edst,
    int* __restrict__ counts, int* __restrict__ bcur, int2* __restrict__ bstore) {
    __shared__ int lhist[NBUCK], lbase[NBUCK], gbase[NBUCK], lcur[NBUCK];
    __shared__ int2 stage[PASSA_CHUNK];    // 32 KB
    const int tid = threadIdx.x;
    if (tid < NBUCK) lhist[tid] = 0;
    __syncthreads();

    const int base = blockIdx.x * PASSA_CHUNK;
    const int nedge = min(PASSA_CHUNK, N_EDGES - base);
    // N_EDGES % 16 == 0, so each thread's 16-edge chunk is all-or-nothing.
    const bool act = (tid * 16) < nedge;
    int s[16], d[16], bk[16];
    if (act) {
        const int4* s4 = (const int4*)(esrc + base + tid * 16);
        const int4* d4 = (const int4*)(edst + base + tid * 16);
#pragma unroll
        for (int t = 0; t < 4; ++t) {
            int4 sv = s4[t], dv = d4[t];
            s[t * 4 + 0] = sv.x; s[t * 4 + 1] = sv.y; s[t * 4 + 2] = sv.z; s[t * 4 + 3] = sv.w;
            d[t * 4 + 0] = dv.x; d[t * 4 + 1] = dv.y; d[t * 4 + 2] = dv.z; d[t * 4 + 3] = dv.w;
        }
#pragma unroll
        for (int u = 0; u < 16; ++u) {
            bk[u] = (int)((unsigned)d[u] / BUCK_NODES);
            atomicAdd(&counts[d[u]], 1);        // degree histogram (global)
            atomicAdd(&lhist[bk[u]], 1);        // block-local bucket counts (LDS)
        }
    }
    __syncthreads();
    if (tid == 0) {
        int run = 0;
#pragma unroll
        for (int b = 0; b < NBUCK; ++b) { lbase[b] = run; lcur[b] = run; run += lhist[b]; }
    }
    if (tid < NBUCK) gbase[tid] = atomicAdd(&bcur[tid], lhist[tid]);
    __syncthreads();
    if (act) {
#pragma unroll
        for (int u = 0; u < 16; ++u) {
            int p = atomicAdd(&lcur[bk[u]], 1);
            stage[p] = make_int2(s[u], d[u]);
        }
    }
    __syncthreads();
    // write out: LDS position p -> global bstore[b*CAP + gbase[b] + (p - lbase[b])]
    for (int p = tid; p < nedge; p += 256) {
        int2 e = stage[p];
        int b = (int)((unsigned)e.y / BUCK_NODES);
        int gp = gbase[b] + (p - lbase[b]);
        if (gp < BUCK_CAP) bstore[(size_t)b * BUCK_CAP + gp] = e;
    }
}

// ---------------- CSR build: pass B — per-bucket fine scatter ----------------

__global__ __launch_bounds__(256) void fill_bucket_kernel(
    const int2* __restrict__ bstore, const int* __restrict__ bcnt,
    const int* __restrict__ off, int* __restrict__ cursor, int* __restrict__ csr) {
    const int bk = blockIdx.x & (NBUCK - 1);
    const int sub = blockIdx.x >> 4;
    const int n = bcnt[bk];
    const int2* ep = bstore + (size_t)bk * BUCK_CAP;
    for (int i = sub * 256 + threadIdx.x; i < n; i += 256 * FILL_SUBS) {
        int2 e = ep[i];
        int p = atomicAdd(&cursor[e.y], 1);
        csr[off[e.y] + p] = e.x;
    }
}

// ---------------- prefix scans (unchanged) ----------------

__global__ void scan1_kernel(const int* __restrict__ counts, int* __restrict__ bsums) {
    __shared__ int wsum[4];
    int base = blockIdx.x * SCAN_CHUNK + threadIdx.x * 4;
    int s = 0;
    if (base + 4 <= N_NODES) {
        int4 v = *(const int4*)(counts + base);
        s = v.x + v.y + v.z + v.w;
    } else {
        for (int j = 0; j < 4; ++j) if (base + j < N_NODES) s += counts[base + j];
    }
    for (int d = 32; d > 0; d >>= 1) s += __shfl_down(s, d, 64);
    if ((threadIdx.x & 63) == 0) wsum[threadIdx.x >> 6] = s;
    __syncthreads();
    if (threadIdx.x == 0) bsums[blockIdx.x] = wsum[0] + wsum[1] + wsum[2] + wsum[3];
}

__global__ void scan2_kernel(const int* __restrict__ bsums, int* __restrict__ boffs) {
    __shared__ int sh[128];
    int i = threadIdx.x;
    int v = (i < SCAN_NB) ? bsums[i] : 0;
    sh[i] = v;
    __syncthreads();
    for (int d = 1; d < 128; d <<= 1) {
        int t = (i >= d) ? sh[i - d] : 0;
        __syncthreads();
        sh[i] += t;
        __syncthreads();
    }
    if (i < SCAN_NB) boffs[i] = sh[i] - v;
}

__global__ void scan3_kernel(const int* __restrict__ counts, const int* __restrict__ boffs,
                             int* __restrict__ off) {
    __shared__ int sh[256];
    int tid = threadIdx.x;
    int base = blockIdx.x * SCAN_CHUNK + tid * 4;
    int c0 = 0, c1 = 0, c2 = 0, c3 = 0;
    if (base + 4 <= N_NODES) {
        int4 v = *(const int4*)(counts + base);
        c0 = v.x; c1 = v.y; c2 = v.z; c3 = v.w;
    } else {
        if (base + 0 < N_NODES) c0 = counts[base + 0];
        if (base + 1 < N_NODES) c1 = counts[base + 1];
        if (base + 2 < N_NODES) c2 = counts[base + 2];
        if (base + 3 < N_NODES) c3 = counts[base + 3];
    }
    int ts = c0 + c1 + c2 + c3;
    sh[tid] = ts;
    __syncthreads();
    for (int d = 1; d < 256; d <<= 1) {
        int t = (tid >= d) ? sh[tid - d] : 0;
        __syncthreads();
        sh[tid] += t;
        __syncthreads();
    }
    int run = boffs[blockIdx.x] + sh[tid] - ts;
    if (base + 0 < N_NODES) off[base + 0] = run; run += c0;
    if (base + 1 < N_NODES) off[base + 1] = run; run += c1;
    if (base + 2 < N_NODES) off[base + 2] = run; run += c2;
    if (base + 3 < N_NODES) off[base + 3] = run;
    if (blockIdx.x == 0 && tid == 0) off[N_NODES] = N_EDGES;
}

// ---------------- x fp32 -> bf16 + fp8 ----------------

__global__ void convert_x_kernel(const float* __restrict__ x, bf16* __restrict__ xb,
                                 unsigned char* __restrict__ xf8) {
    int i = blockIdx.x * blockDim.x + threadIdx.x;
    int total4 = N_NODES * IN_DIM / 4;
    if (i >= total4) return;
    float4 v = ((const float4*)x)[i];
    ushort4 r;
    r.x = f2bf(v.x); r.y = f2bf(v.y); r.z = f2bf(v.z); r.w = f2bf(v.w);
    ((ushort4*)xb)[i] = r;
    ((unsigned int*)xf8)[i] = pack4_fp8(v.x, v.y, v.z, v.w);
}

// ---------------- combined weight prep ----------------

__global__ void prep_weights_kernel(const float* __restrict__ W1l, const float* __restrict__ W1r,
                                    const float* __restrict__ W2l, const float* __restrict__ W2r,
                                    const float* __restrict__ Wfc,
                                    bf16* __restrict__ w1lt, bf16* __restrict__ w1rt,
                                    bf16* __restrict__ w2lt, bf16* __restrict__ w2rt,
                                    bf16* __restrict__ wfct) {
    const int S1 = IN_DIM * HID;   // 32768
    const int S2 = HID * HID;      // 65536
    const int S3 = HID * N_CLS;    // 8192
    int i = blockIdx.x * blockDim.x + threadIdx.x;
    if (i < 2 * S1 + 2 * S2) {
        const float* W; bf16* Wt; int K, idx;
        if (i < S1)          { W = W1l; Wt = w1lt; K = IN_DIM; idx = i; }
        else if (i < 2 * S1) { W = W1r; Wt = w1rt; K = IN_DIM; idx = i - S1; }
        else if (i < 2 * S1 + S2) { W = W2l; Wt = w2lt; K = HID; idx = i - 2 * S1; }
        else                 { W = W2r; Wt = w2rt; K = HID; idx = i - 2 * S1 - S2; }
        int k = idx / HID, n = idx - k * HID;
        Wt[(size_t)n * K + k] = f2bf(W[idx]);
    } else if (i < 2 * S1 + 2 * S2 + S3) {
        int idx = i - 2 * S1 - 2 * S2;       // idx = k*32 + n
        int k = idx >> 5, n = idx & 31;
        wfct[(size_t)n * HID + k] = f2bf(Wfc[idx]);
    }
}

// ---------------- mean aggregation (fp8 gathers, sub-wave per node, x4 unroll) ----------------

__global__ void aggregate1_kernel(const unsigned char* __restrict__ xf8, const int* __restrict__ off,
                                  const int* __restrict__ csr, bf16* __restrict__ out) {
    int t = blockIdx.x * blockDim.x + threadIdx.x;
    int node = t >> 4;
    int sl = t & 15;
    if (node >= N_NODES) return;
    int s = off[node], e = off[node + 1];
    float inv = 1.0f / (float)max(e - s, 1);
    const uint2* f = (const uint2*)xf8;   // row = 16 uint2
    float a[8] = {0.f, 0.f, 0.f, 0.f, 0.f, 0.f, 0.f, 0.f};
    int i = s;
    for (; i + 4 <= e; i += 4) {
        int u0 = csr[i], u1 = csr[i + 1], u2 = csr[i + 2], u3 = csr[i + 3];
        uint2 w0 = f[(size_t)u0 * 16 + sl];
        uint2 w1 = f[(size_t)u1 * 16 + sl];
        uint2 w2 = f[(size_t)u2 * 16 + sl];
        uint2 w3 = f[(size_t)u3 * 16 + sl];
        acc8_fp8(w0, a); acc8_fp8(w1, a); acc8_fp8(w2, a); acc8_fp8(w3, a);
    }
    for (; i < e; ++i) {
        uint2 w = f[(size_t)csr[i] * 16 + sl];
        acc8_fp8(w, a);
    }
    uint4 r;
    r.x = pack2(a[0] * inv, a[1] * inv);
    r.y = pack2(a[2] * inv, a[3] * inv);
    r.z = pack2(a[4] * inv, a[5] * inv);
    r.w = pack2(a[6] * inv, a[7] * inv);
    ((uint4*)out)[(size_t)node * 16 + sl] = r;
}

__global__ void aggregate2_kernel(const unsigned char* __restrict__ hf8, const int* __restrict__ off,
                                  const int* __restrict__ csr, bf16* __restrict__ out) {
    int t = blockIdx.x * blockDim.x + threadIdx.x;
    int node = t >> 5;
    int sl = t & 31;
    if (node >= N_NODES) return;
    int s = off[node], e = off[node + 1];
    float inv = 1.0f / (float)max(e - s, 1);
    const uint2* f = (const uint2*)hf8;   // row = 32 uint2
    float a[8] = {0.f, 0.f, 0.f, 0.f, 0.f, 0.f, 0.f, 0.f};
    int i = s;
    for (; i + 4 <= e; i += 4) {
        int u0 = csr[i], u1 = csr[i + 1], u2 = csr[i + 2], u3 = csr[i + 3];
        uint2 w0 = f[(size_t)u0 * 32 + sl];
        uint2 w1 = f[(size_t)u1 * 32 + sl];
        uint2 w2 = f[(size_t)u2 * 32 + sl];
        uint2 w3 = f[(size_t)u3 * 32 + sl];
        acc8_fp8(w0, a); acc8_fp8(w1, a); acc8_fp8(w2, a); acc8_fp8(w3, a);
    }
    for (; i < e; ++i) {
        uint2 w = f[(size_t)csr[i] * 32 + sl];
        acc8_fp8(w, a);
    }
    uint4 r;
    r.x = pack2(a[0] * inv, a[1] * inv);
    r.y = pack2(a[2] * inv, a[3] * inv);
    r.z = pack2(a[4] * inv, a[5] * inv);
    r.w = pack2(a[6] * inv, a[7] * inv);
    ((uint4*)out)[(size_t)node * 32 + sl] = r;
}

// ---------------- MFMA dual GEMM: global_load_lds + 3-buffer 2-deep prefetch ----------------
// Linear 128x32 bf16 tiles (64B rows) in LDS: ds_read_b128 fragment pattern is
// bank-balanced at the wave64 8-cycle minimum (verified by hand), no pad/swizzle needed.
// Hot loop uses raw s_barrier + counted vmcnt (never drains to 0 mid-loop) so two
// tiles' loads stay in flight across barriers — __syncthreads would force vmcnt(0).

#define AT_SZ 4096   // bf16 per tile buffer (128 rows x 32)

__device__ __forceinline__ void stage_tile(
    const bf16* __restrict__ Ap, const bf16* __restrict__ Wp, int K, int k0,
    int tile_m, int tile_n, int M, int wave, int lane,
    bf16* bufA, bf16* bufW) {
    // tile = 8 KB; wave w covers bytes [w*2048,(w+1)*2048) via 2 x 1KB gload_lds
#pragma unroll
    for (int is = 0; is < 2; ++is) {
        int lin = (wave * 2 + is) * 1024 + lane * 16;   // byte offset in tile
        int row = lin >> 6;                              // 64B per row
        int seg = (lin >> 4) & 3;
        int ga = min(tile_m + row, M - 1);               // clamp OOB rows (results discarded)
        gload16(Ap + (size_t)ga * K + k0 + seg * 8, (char*)bufA + (wave * 2 + is) * 1024);
        gload16(Wp + (size_t)(tile_n + row) * K + k0 + seg * 8, (char*)bufW + (wave * 2 + is) * 1024);
    }
}

__global__ __launch_bounds__(256) void gemm_dual_mfma(
    const bf16* __restrict__ A, const bf16* __restrict__ WtA, int KA,
    const bf16* __restrict__ Bm, const bf16* __restrict__ WtB, int KB,
    const float* __restrict__ bias, bf16* __restrict__ C, int M,
    float* __restrict__ psum, float* __restrict__ psq) {
    __shared__ bf16 As[3 * AT_SZ];
    __shared__ bf16 Ws[3 * AT_SZ];
    __shared__ float sred[4][64];
    __shared__ float qred[4][64];
    const int tid = threadIdx.x;
    const int lane = tid & 63;
    const int wave = tid >> 6;
    const int rw = (wave >> 1) * 64;
    const int cw = (wave & 1) * 64;
    const int lrow = lane & 15;
    const int quad = lane >> 4;
    const int tile_m = blockIdx.y * 128;
    const int tile_n = blockIdx.x * 128;

    float4v acc[4][4];
#pragma unroll
    for (int i = 0; i < 4; ++i)
#pragma unroll
        for (int j = 0; j < 4; ++j) acc[i][j] = (float4v){0.f, 0.f, 0.f, 0.f};

    const int NTA = KA >> 5;
    const int NT = NTA + (KB >> 5);
    // tile source resolver (uniform across block)
    auto tsrc = [&](int t, const bf16*& Ap, const bf16*& Wp, int& K, int& k0) {
        if (t < NTA) { Ap = A;  Wp = WtA; K = KA; k0 = t << 5; }
        else         { Ap = Bm; Wp = WtB; K = KB; k0 = (t - NTA) << 5; }
    };

    // prologue: stage tiles 0 and 1 (NT >= 4 always)
#pragma unroll
    for (int t = 0; t < 2; ++t) {
        const bf16 *Ap, *Wp; int K, k0; tsrc(t, Ap, Wp, K, k0);
        stage_tile(Ap, Wp, K, k0, tile_m, tile_n, M, wave, lane,
                   As + t * AT_SZ, Ws + t * AT_SZ);
    }

    for (int t = 0; t < NT; ++t) {
        if (t + 2 < NT) {
            const bf16 *Ap, *Wp; int K, k0; tsrc(t + 2, Ap, Wp, K, k0);
            int b = (t + 2) % 3;
            stage_tile(Ap, Wp, K, k0, tile_m, tile_n, M, wave, lane,
                       As + b * AT_SZ, Ws + b * AT_SZ);
        }
        // per-wave: 4 vmem issues per stage; keep up to 2 future tiles (8) in flight
        if (t + 2 < NT)      asm volatile("s_waitcnt vmcnt(8)" ::: "memory");
        else if (t + 1 < NT) asm volatile("s_waitcnt vmcnt(4)" ::: "memory");
        else                 asm volatile("s_waitcnt vmcnt(0)" ::: "memory");
        __builtin_amdgcn_s_barrier();
        asm volatile("" ::: "memory");

        const bf16* bA = As + (t % 3) * AT_SZ;
        const bf16* bW = Ws + (t % 3) * AT_SZ;
        short8 a[4], b[4];
#pragma unroll
        for (int i = 0; i < 4; ++i)
            a[i] = *(const short8*)(bA + (rw + i * 16 + lrow) * 32 + quad * 8);
#pragma unroll
        for (int j = 0; j < 4; ++j)
            b[j] = *(const short8*)(bW + (cw + j * 16 + lrow) * 32 + quad * 8);
#pragma unroll
        for (int i = 0; i < 4; ++i)
#pragma unroll
            for (int j = 0; j < 4; ++j)
                acc[i][j] = __builtin_amdgcn_mfma_f32_16x16x32_bf16(a[i], b[j], acc[i][j], 0, 0, 0);

        asm volatile("" ::: "memory");
        __builtin_amdgcn_s_barrier();   // protect buf (t%3) from stage at t+1 (writes (t+3)%3)
    }

    // ---- epilogue: C/D layout col=lane&15, row=quad*4+reg [verified m89] ----
    // Per-wave LDS slice (16x64 bf16 = 2 KB) -> coalesced 16B global stores.
    // j-block slot XOR'd with writer quad (= row>>2) -> conflict-free scalar writes.
    bf16* slice = As + wave * 1024;
    float bvj[4];
#pragma unroll
    for (int j = 0; j < 4; ++j) bvj[j] = bias[tile_n + cw + j * 16 + lrow];
    float cs[4] = {0.f, 0.f, 0.f, 0.f}, cq[4] = {0.f, 0.f, 0.f, 0.f};

#pragma unroll
    for (int i = 0; i < 4; ++i) {
#pragma unroll
        for (int j = 0; j < 4; ++j) {
#pragma unroll
            for (int r = 0; r < 4; ++r) {
                int row = tile_m + rw + i * 16 + quad * 4 + r;
                float v = acc[i][j][r] + bvj[j];
                if (row < M) { cs[j] += v; cq[j] += v * v; }
                slice[(quad * 4 + r) * 64 + ((j ^ quad) * 16) + lrow] = f2bf(v);
            }
        }
        __syncthreads();
        // readback: 128 uint4 chunks (16 rows x 8 chunks), lane handles 2
#pragma unroll
        for (int c = 0; c < 2; ++c) {
            int ch = lane + c * 64;
            int lr = ch >> 3, sg = ch & 7;
            int grow = tile_m + rw + i * 16 + lr;
            if (grow < M) {
                const bf16* srcp = slice + lr * 64 + (((sg >> 1) ^ (lr >> 2)) << 4) + ((sg & 1) << 3);
                uint4 v = *(const uint4*)srcp;
                *(uint4*)(C + (size_t)grow * HID + tile_n + cw + sg * 8) = v;
            }
        }
        __syncthreads();
    }

    // reduce across the 4 quads that share each (j,lrow) column
#pragma unroll
    for (int j = 0; j < 4; ++j) {
        cs[j] += __shfl_xor(cs[j], 16, 64); cs[j] += __shfl_xor(cs[j], 32, 64);
        cq[j] += __shfl_xor(cq[j], 16, 64); cq[j] += __shfl_xor(cq[j], 32, 64);
    }
    if (quad == 0) {
#pragma unroll
        for (int j = 0; j < 4; ++j) {
            sred[wave][j * 16 + lrow] = cs[j];
            qred[wave][j * 16 + lrow] = cq[j];
        }
    }
    __syncthreads();
    int bid = blockIdx.y * gridDim.x + blockIdx.x;
    if (tid < 128) {
        int grp = tid >> 6, idx = tid & 63;
        psum[(size_t)bid * 128 + tid] = sred[grp][idx] + sred[grp + 2][idx];
    } else {
        int t = tid - 128;
        int grp = t >> 6, idx = t & 63;
        psq[(size_t)bid * 128 + t] = qred[grp][idx] + qred[grp + 2][idx];
    }
}

// reduce per-block partials -> stats[0..255]=sum, stats[256..511]=sumsq
__global__ void bn_finalize_kernel(const float* __restrict__ psum, const float* __restrict__ psq,
                                   float* __restrict__ stats, int nby) {
    const float* src = blockIdx.y ? psq : psum;
    int c = threadIdx.x;           // 0..255 = global column
    int bx = c >> 7, cl = c & 127;
    int per = (nby + gridDim.x - 1) / gridDim.x;
    int b0 = blockIdx.x * per, b1 = min(b0 + per, nby);
    float s = 0.f;
    for (int by = b0; by < b1; ++by) s += src[(size_t)(by * 2 + bx) * 128 + cl];
    atomicAdd(&stats[blockIdx.y * HID + c], s);
}

// ---------------- BN apply + ReLU (layer 1; also emits fp8 copy for gather) ----------------

__global__ void bn_apply_relu_kernel(bf16* __restrict__ h, unsigned char* __restrict__ hf8,
                                     const float* __restrict__ stats,
                                     const float* __restrict__ g, const float* __restrict__ be,
                                     int M) {
    int i4 = blockIdx.x * blockDim.x + threadIdx.x;
    int total4 = M * (HID / 4);
    if (i4 >= total4) return;
    int col4 = i4 & (HID / 4 - 1);
    ushort4 v = ((const ushort4*)h)[i4];
    float invN = 1.0f / (float)M;
    float o[4] = {bf2f(v.x), bf2f(v.y), bf2f(v.z), bf2f(v.w)};
#pragma unroll
    for (int j = 0; j < 4; ++j) {
        int col = col4 * 4 + j;
        float mu = stats[col] * invN;
        float var = stats[HID + col] * invN - mu * mu;
        float sc = rsqrtf(var + BN_EPS) * g[col];
        float val = (o[j] - mu) * sc + be[col];
        o[j] = val > 0.f ? val : 0.f;
    }
    ushort4 r;
    r.x = f2bf(o[0]); r.y = f2bf(o[1]); r.z = f2bf(o[2]); r.w = f2bf(o[3]);
    ((ushort4*)h)[i4] = r;
    ((unsigned int*)hf8)[i4] = pack4_fp8(o[0], o[1], o[2], o[3]);
}

// ---------------- final FC (MFMA) with fused BN2+ReLU ----------------

#define BSTR 264   // 256 + 8 pad

__global__ __launch_bounds__(256) void fc_bn_mfma_kernel(
    const bf16* __restrict__ h, const float* __restrict__ stats,
    const float* __restrict__ g, const float* __restrict__ be,
    const bf16* __restrict__ WfcT, const float* __restrict__ bfc,
    float* __restrict__ out, int M) {
    __shared__ bf16 Bs[32 * BSTR];
    __shared__ float sc_s[HID], sh_s[HID];
    int tid = threadIdx.x;
    for (int i = tid; i < 32 * 32; i += 256) {   // 1024 16B chunks
        int rrow = i >> 5, seg = i & 31;
        *(uint4*)(Bs + rrow * BSTR + seg * 8) = *(const uint4*)(WfcT + (size_t)rrow * HID + seg * 8);
    }
    {
        float invN = 1.0f / (float)M;
        float mu = stats[tid] * invN;
        float var = stats[HID + tid] * invN - mu * mu;
        float s = rsqrtf(var + BN_EPS) * g[tid];
        sc_s[tid] = s;
        sh_s[tid] = be[tid] - mu * s;
    }
    __syncthreads();
    int wave = tid >> 6, lane = tid & 63, lrow = lane & 15, quad = lane >> 4;
    int row = blockIdx.x * 64 + wave * 16 + lrow;
    const bf16* hrow = h + (size_t)row * HID;
    float4v acc0 = {0.f, 0.f, 0.f, 0.f}, acc1 = {0.f, 0.f, 0.f, 0.f};
#pragma unroll
    for (int ks = 0; ks < 8; ++ks) {
        int k0 = ks * 32 + quad * 8;
        uint4 av = {0u, 0u, 0u, 0u};
        if (row < M) av = *(const uint4*)(hrow + k0);
        union { unsigned int u[4]; short8 s8; } cvt;
        unsigned int* avp = (unsigned int*)&av;
#pragma unroll
        for (int t = 0; t < 4; ++t) {
            int k = k0 + t * 2;
            float v0 = blo(avp[t]) * sc_s[k] + sh_s[k];
            float v1 = bhi(avp[t]) * sc_s[k + 1] + sh_s[k + 1];
            v0 = v0 > 0.f ? v0 : 0.f;
            v1 = v1 > 0.f ? v1 : 0.f;
            cvt.u[t] = pack2(v0, v1);
        }
        short8 b0 = *(const short8*)(Bs + lrow * BSTR + k0);
        short8 b1 = *(const short8*)(Bs + (16 + lrow) * BSTR + k0);
        acc0 = __builtin_amdgcn_mfma_f32_16x16x32_bf16(cvt.s8, b0, acc0, 0, 0, 0);
        acc1 = __builtin_amdgcn_mfma_f32_16x16x32_bf16(cvt.s8, b1, acc1, 0, 0, 0);
    }
    int orow = blockIdx.x * 64 + wave * 16 + quad * 4;
    float bv0 = bfc[lrow], bv1 = bfc[16 + lrow];
#pragma unroll
    for (int r = 0; r < 4; ++r) {
        int rr = orow + r;
        if (rr < M) {
            out[(size_t)rr * N_CLS + lrow] = acc0[r] + bv0;
            out[(size_t)rr * N_CLS + 16 + lrow] = acc1[r] + bv1;
        }
    }
}

// ---------------- launch ----------------

extern "C" void kernel_launch(void* const* d_in, const int* in_sizes, int n_in,
                              void* d_out, int out_size, void* d_ws, size_t ws_size,
                              hipStream_t stream) {
    const float* x   = (const float*)d_in[0];
    const int* esrc  = (const int*)d_in[1];
    const int* edst  = (const int*)d_in[2];
    const float* W1l = (const float*)d_in[3];
    const float* b1  = (const float*)d_in[4];
    const float* W1r = (const float*)d_in[5];
    const float* g1  = (const float*)d_in[6];
    const float* be1 = (const float*)d_in[7];
    const float* W2l = (const float*)d_in[8];
    const float* b2  = (const float*)d_in[9];
    const float* W2r = (const float*)d_in[10];
    const float* g2  = (const float*)d_in[11];
    const float* be2 = (const float*)d_in[12];
    const float* Wfc = (const float*)d_in[13];
    const float* bfc = (const float*)d_in[14];
    float* out = (float*)d_out;

    char* ws = (char*)d_ws;
    size_t o = 0;
    auto carve = [&](size_t bytes) {
        char* p = ws + o;
        o = (o + bytes + 255) & ~(size_t)255;
        return p;
    };
    int*   off    = (int*)carve((N_NODES + 1) * sizeof(int));
    int*   cursor = (int*)carve(N_NODES * sizeof(int));
    int*   csr    = (int*)carve(N_EDGES * sizeof(int));
    int*   bsums  = (int*)carve(SCAN_NB * sizeof(int));
    int*   boffs  = (int*)carve(SCAN_NB * sizeof(int));
    int*   bcur   = (int*)carve(NBUCK * sizeof(int));
    float* stats1 = (float*)carve(2 * HID * sizeof(float));
    float* stats2 = (float*)carve(2 * HID * sizeof(float));
    float* psum   = (float*)carve((size_t)GEMM_NB * 128 * sizeof(float));
    float* psq    = (float*)carve((size_t)GEMM_NB * 128 * sizeof(float));
    bf16*  w1lt   = (bf16*)carve((size_t)IN_DIM * HID * sizeof(bf16));
    bf16*  w1rt   = (bf16*)carve((size_t)IN_DIM * HID * sizeof(bf16));
    bf16*  w2lt   = (bf16*)carve((size_t)HID * HID * sizeof(bf16));
    bf16*  w2rt   = (bf16*)carve((size_t)HID * HID * sizeof(bf16));
    bf16*  wfct   = (bf16*)carve((size_t)N_CLS * HID * sizeof(bf16));
    bf16*  agg    = (bf16*)carve((size_t)N_NODES * HID * sizeof(bf16));
    bf16*  h1     = (bf16*)carve((size_t)N_NODES * HID * sizeof(bf16));
    bf16*  h2     = (bf16*)carve((size_t)N_NODES * HID * sizeof(bf16));
    // overlays inside the h2 region (lifetimes stream-ordered disjoint):
    //   xb  = h2[0   : 25.6MB]  bf16 x   — dead after gemm1
    //   xf8 = h2[25.6: 38.4MB]  fp8 x    — dead after aggregate1
    //   h1f8= h2[0   : 25.6MB]  fp8 bn(h1) — written post-gemm1, read by aggregate2,
    //                                        then gemm2 overwrites h2
    bf16*          xb   = h2;
    unsigned char* xf8  = (unsigned char*)h2 + (size_t)N_NODES * IN_DIM * sizeof(bf16);
    unsigned char* h1f8 = (unsigned char*)h2;
    // overlay inside the agg region (dead until aggregate1 writes it):
    //   bstore = 16 buckets x 112K edges x 8B = 14.3 MB < 51.2 MB
    int2*          bstore = (int2*)agg;

    if (o > ws_size) return;  // clean fail instead of fault

    hipMemsetAsync(cursor, 0, N_NODES * sizeof(int), stream);
    hipMemsetAsync(bcur, 0, NBUCK * sizeof(int), stream);
    hipMemsetAsync(stats1, 0, 2 * HID * sizeof(float), stream);
    hipMemsetAsync(stats2, 0, 2 * HID * sizeof(float), stream);

    // CSR build: bucketed two-phase scatter (pass A folds in the degree histogram)
    bucket_scatter_kernel<<<PASSA_NB, 256, 0, stream>>>(esrc, edst, cursor, bcur, bstore);
    scan1_kernel<<<SCAN_NB, 256, 0, stream>>>(cursor, bsums);
    scan2_kernel<<<1, 128, 0, stream>>>(bsums, boffs);
    scan3_kernel<<<SCAN_NB, 256, 0, stream>>>(cursor, boffs, off);
    hipMemsetAsync(cursor, 0, N_NODES * sizeof(int), stream);
    fill_bucket_kernel<<<NBUCK * FILL_SUBS, 256, 0, stream>>>(bstore, bcur, off, cursor, csr);

    // prep: x -> bf16 + fp8, all weights -> bf16 transposed
    convert_x_kernel<<<(N_NODES * IN_DIM / 4 + 255) / 256, 256, 0, stream>>>(x, xb, xf8);
    {
        int total = 2 * IN_DIM * HID + 2 * HID * HID + HID * N_CLS;
        prep_weights_kernel<<<(total + 255) / 256, 256, 0, stream>>>(
            W1l, W1r, W2l, W2r, Wfc, w1lt, w1rt, w2lt, w2rt, wfct);
    }

    const dim3 ggrid(HID / 128, GEMM_NBY);

    // ---- layer 1 ----
    aggregate1_kernel<<<(N_NODES * 16 + 255) / 256, 256, 0, stream>>>(xf8, off, csr, agg);
    gemm_dual_mfma<<<ggrid, 256, 0, stream>>>(
        agg, w1lt, IN_DIM, xb, w1rt, IN_DIM, b1, h1, N_NODES, psum, psq);
    bn_finalize_kernel<<<dim3(8, 2), 256, 0, stream>>>(psum, psq, stats1, GEMM_NBY);
    {
        int total4 = N_NODES * (HID / 4);
        bn_apply_relu_kernel<<<(total4 + 255) / 256, 256, 0, stream>>>(h1, h1f8, stats1, g1, be1, N_NODES);
    }

    // ---- layer 2 ----
    aggregate2_kernel<<<(N_NODES * 32 + 255) / 256, 256, 0, stream>>>(h1f8, off, csr, agg);
    gemm_dual_mfma<<<ggrid, 256, 0, stream>>>(
        agg, w2lt, HID, h1, w2rt, HID, b2, h2, N_NODES, psum, psq);
    bn_finalize_kernel<<<dim3(8, 2), 256, 0, stream>>>(psum, psq, stats2, GEMM_NBY);

    // ---- final FC (MFMA) with fused BN2+ReLU ----
    fc_bn_mfma_kernel<<<(N_NODES + 63) / 64, 256, 0, stream>>>(
        h2, stats2, g2, be2, wfct, bfc, out, N_NODES);
}

// Round 3
// 512.234 us; speedup vs baseline: 1.1253x; 1.0877x over previous
//
#include <hip/hip_runtime.h>

#define N_NODES 100000
#define N_EDGES 1600000
#define IN_DIM 128
#define HID 256
#define N_CLS 32
#define BN_EPS 1e-5f

#define SCAN_CHUNK 1024
#define SCAN_NB ((N_NODES + SCAN_CHUNK - 1) / SCAN_CHUNK)   // 98
#define GEMM_NBY ((N_NODES + 127) / 128)                    // 782
#define GEMM_NB (GEMM_NBY * 2)                              // 1564 blocks (2 n-tiles)

// ---- bucketed CSR fill parameters ----
#define NBUCK 16
#define BUCK_NODES 6250        // 16 * 6250 = 100000 exactly
#define BUCK_CAP 112000        // expected 100K/bucket, sd ~306 -> huge margin
#define PASSA_CHUNK 2048       // edges staged per block (16 KB LDS)
#define PASSA_NB ((N_EDGES + PASSA_CHUNK - 1) / PASSA_CHUNK)  // 782
#define FILL_SUBS 64           // blocks per bucket in pass B
#define HSUBS 16               // histogram slices per bucket

typedef unsigned short bf16;
typedef __attribute__((ext_vector_type(8))) short short8;
typedef __attribute__((ext_vector_type(4))) float float4v;
typedef __attribute__((ext_vector_type(2))) float floatx2;

__device__ __forceinline__ float bf2f(bf16 h) {
    return __uint_as_float(((unsigned int)h) << 16);
}
__device__ __forceinline__ bf16 f2bf(float f) {
    unsigned int u = __float_as_uint(f);
    u += 0x7FFFu + ((u >> 16) & 1u);   // round-to-nearest-even
    return (bf16)(u >> 16);
}
__device__ __forceinline__ float blo(unsigned int u) { return __uint_as_float(u << 16); }
__device__ __forceinline__ float bhi(unsigned int u) { return __uint_as_float(u & 0xFFFF0000u); }
__device__ __forceinline__ unsigned int pack2(float lo, float hi) {
    return (unsigned int)f2bf(lo) | ((unsigned int)f2bf(hi) << 16);
}

// fp8 (OCP e4m3 on gfx950) hardware conversions
__device__ __forceinline__ void acc8_fp8(uint2 w, float* a) {
    floatx2 f0 = __builtin_amdgcn_cvt_pk_f32_fp8(w.x, false);
    floatx2 f1 = __builtin_amdgcn_cvt_pk_f32_fp8(w.x, true);
    floatx2 f2 = __builtin_amdgcn_cvt_pk_f32_fp8(w.y, false);
    floatx2 f3 = __builtin_amdgcn_cvt_pk_f32_fp8(w.y, true);
    a[0] += f0.x; a[1] += f0.y; a[2] += f1.x; a[3] += f1.y;
    a[4] += f2.x; a[5] += f2.y; a[6] += f3.x; a[7] += f3.y;
}
__device__ __forceinline__ unsigned int pack4_fp8(float a, float b, float c, float d) {
    int p = 0;
    p = __builtin_amdgcn_cvt_pk_fp8_f32(a, b, p, false);
    p = __builtin_amdgcn_cvt_pk_fp8_f32(c, d, p, true);
    return (unsigned int)p;
}

// async global->LDS, 16B per lane, wave-uniform LDS base + lane*16
__device__ __forceinline__ void gload16(const void* g, void* l) {
    __builtin_amdgcn_global_load_lds(
        (const __attribute__((address_space(1))) void*)g,
        (__attribute__((address_space(3))) void*)l, 16, 0, 0);
}

// ---------------- CSR build: pass A — bucket scatter (no global atomics) ----------------
// Streams edges once. Per block: LDS-stage 2048 (src,dst) pairs grouped by dst-bucket,
// reserve per-bucket global ranges with one atomic per bucket, write contiguous runs.

__global__ __launch_bounds__(256) void bucket_scatter_kernel(
    const int* __restrict__ esrc, const int* __restrict__ edst,
    int* __restrict__ bcur, int2* __restrict__ bstore) {
    __shared__ int lhist[NBUCK], lbase[NBUCK], gbase[NBUCK], lcur[NBUCK];
    __shared__ int2 stage[PASSA_CHUNK];    // 16 KB
    const int tid = threadIdx.x;
    if (tid < NBUCK) lhist[tid] = 0;
    __syncthreads();

    const int base = blockIdx.x * PASSA_CHUNK;
    const int nedge = min(PASSA_CHUNK, N_EDGES - base);
    // N_EDGES % 8 == 0, so each thread's 8-edge chunk is all-or-nothing.
    const bool act = (tid * 8) < nedge;
    int s[8], d[8], bk[8];
    if (act) {
        const int4* s4 = (const int4*)(esrc + base + tid * 8);
        const int4* d4 = (const int4*)(edst + base + tid * 8);
#pragma unroll
        for (int t = 0; t < 2; ++t) {
            int4 sv = s4[t], dv = d4[t];
            s[t * 4 + 0] = sv.x; s[t * 4 + 1] = sv.y; s[t * 4 + 2] = sv.z; s[t * 4 + 3] = sv.w;
            d[t * 4 + 0] = dv.x; d[t * 4 + 1] = dv.y; d[t * 4 + 2] = dv.z; d[t * 4 + 3] = dv.w;
        }
#pragma unroll
        for (int u = 0; u < 8; ++u) {
            bk[u] = (int)((unsigned)d[u] / BUCK_NODES);
            atomicAdd(&lhist[bk[u]], 1);        // block-local bucket counts (LDS only)
        }
    }
    __syncthreads();
    if (tid == 0) {
        int run = 0;
#pragma unroll
        for (int b = 0; b < NBUCK; ++b) { lbase[b] = run; lcur[b] = run; run += lhist[b]; }
    }
    if (tid < NBUCK) gbase[tid] = atomicAdd(&bcur[tid], lhist[tid]);
    __syncthreads();
    if (act) {
#pragma unroll
        for (int u = 0; u < 8; ++u) {
            int p = atomicAdd(&lcur[bk[u]], 1);
            stage[p] = make_int2(s[u], d[u]);
        }
    }
    __syncthreads();
    // write out: LDS position p -> global bstore[b*CAP + gbase[b] + (p - lbase[b])]
    for (int p = tid; p < nedge; p += 256) {
        int2 e = stage[p];
        int b = (int)((unsigned)e.y / BUCK_NODES);
        int gp = gbase[b] + (p - lbase[b]);
        if (gp < BUCK_CAP) bstore[(size_t)b * BUCK_CAP + gp] = e;
    }
}

// ---------------- CSR build: per-bucket degree histogram (LDS-privatized) ----------------
// Bucket spans 6250 nodes = 25 KB -> full histogram fits in LDS. 16 slices per bucket
// for parallelism; partial[s][node] streamed out coalesced, no global atomics at all.

__global__ __launch_bounds__(256) void bucket_hist_kernel(
    const int2* __restrict__ bstore, const int* __restrict__ bcnt,
    int* __restrict__ partial) {
    __shared__ int hist[BUCK_NODES];   // 25000 B
    const int bk = blockIdx.x & (NBUCK - 1);
    const int sl = blockIdx.x >> 4;
    for (int i = threadIdx.x; i < BUCK_NODES; i += 256) hist[i] = 0;
    __syncthreads();
    const int n = bcnt[bk];
    const int per = (n + HSUBS - 1) / HSUBS;
    const int i0 = sl * per, i1 = min(i0 + per, n);
    const int2* ep = bstore + (size_t)bk * BUCK_CAP;
    const int nbase = bk * BUCK_NODES;
    for (int i = i0 + threadIdx.x; i < i1; i += 256) {
        atomicAdd(&hist[ep[i].y - nbase], 1);
    }
    __syncthreads();
    int* dst = partial + (size_t)sl * N_NODES + nbase;
    for (int i = threadIdx.x; i < BUCK_NODES; i += 256) dst[i] = hist[i];
}

// ---------------- CSR build: pass B — per-bucket fine scatter ----------------

__global__ __launch_bounds__(256) void fill_bucket_kernel(
    const int2* __restrict__ bstore, const int* __restrict__ bcnt,
    const int* __restrict__ off, int* __restrict__ cursor, int* __restrict__ csr) {
    const int bk = blockIdx.x & (NBUCK - 1);
    const int sub = blockIdx.x >> 4;
    const int n = bcnt[bk];
    const int2* ep = bstore + (size_t)bk * BUCK_CAP;
    for (int i = sub * 256 + threadIdx.x; i < n; i += 256 * FILL_SUBS) {
        int2 e = ep[i];
        int p = atomicAdd(&cursor[e.y], 1);
        csr[off[e.y] + p] = e.x;
    }
}

// ---------------- prefix scans ----------------
// scan1 now also folds the HSUBS partial histograms into the final counts array.

__global__ void scan1_kernel(const int* __restrict__ partial, int* __restrict__ counts,
                             int* __restrict__ bsums) {
    __shared__ int wsum[4];
    int base = blockIdx.x * SCAN_CHUNK + threadIdx.x * 4;
    int c0 = 0, c1 = 0, c2 = 0, c3 = 0;
    if (base + 4 <= N_NODES) {
#pragma unroll
        for (int sl = 0; sl < HSUBS; ++sl) {
            int4 v = *(const int4*)(partial + (size_t)sl * N_NODES + base);
            c0 += v.x; c1 += v.y; c2 += v.z; c3 += v.w;
        }
        int4 w; w.x = c0; w.y = c1; w.z = c2; w.w = c3;
        *(int4*)(counts + base) = w;
    } else {
        for (int j = 0; j < 4; ++j) {
            if (base + j < N_NODES) {
                int c = 0;
                for (int sl = 0; sl < HSUBS; ++sl) c += partial[(size_t)sl * N_NODES + base + j];
                counts[base + j] = c;
                if (j == 0) c0 = c; else if (j == 1) c1 = c; else if (j == 2) c2 = c; else c3 = c;
            }
        }
    }
    int s = c0 + c1 + c2 + c3;
    for (int d = 32; d > 0; d >>= 1) s += __shfl_down(s, d, 64);
    if ((threadIdx.x & 63) == 0) wsum[threadIdx.x >> 6] = s;
    __syncthreads();
    if (threadIdx.x == 0) bsums[blockIdx.x] = wsum[0] + wsum[1] + wsum[2] + wsum[3];
}

__global__ void scan2_kernel(const int* __restrict__ bsums, int* __restrict__ boffs) {
    __shared__ int sh[128];
    int i = threadIdx.x;
    int v = (i < SCAN_NB) ? bsums[i] : 0;
    sh[i] = v;
    __syncthreads();
    for (int d = 1; d < 128; d <<= 1) {
        int t = (i >= d) ? sh[i - d] : 0;
        __syncthreads();
        sh[i] += t;
        __syncthreads();
    }
    if (i < SCAN_NB) boffs[i] = sh[i] - v;
}

__global__ void scan3_kernel(const int* __restrict__ counts, const int* __restrict__ boffs,
                             int* __restrict__ off) {
    __shared__ int sh[256];
    int tid = threadIdx.x;
    int base = blockIdx.x * SCAN_CHUNK + tid * 4;
    int c0 = 0, c1 = 0, c2 = 0, c3 = 0;
    if (base + 4 <= N_NODES) {
        int4 v = *(const int4*)(counts + base);
        c0 = v.x; c1 = v.y; c2 = v.z; c3 = v.w;
    } else {
        if (base + 0 < N_NODES) c0 = counts[base + 0];
        if (base + 1 < N_NODES) c1 = counts[base + 1];
        if (base + 2 < N_NODES) c2 = counts[base + 2];
        if (base + 3 < N_NODES) c3 = counts[base + 3];
    }
    int ts = c0 + c1 + c2 + c3;
    sh[tid] = ts;
    __syncthreads();
    for (int d = 1; d < 256; d <<= 1) {
        int t = (tid >= d) ? sh[tid - d] : 0;
        __syncthreads();
        sh[tid] += t;
        __syncthreads();
    }
    int run = boffs[blockIdx.x] + sh[tid] - ts;
    if (base + 0 < N_NODES) off[base + 0] = run; run += c0;
    if (base + 1 < N_NODES) off[base + 1] = run; run += c1;
    if (base + 2 < N_NODES) off[base + 2] = run; run += c2;
    if (base + 3 < N_NODES) off[base + 3] = run;
    if (blockIdx.x == 0 && tid == 0) off[N_NODES] = N_EDGES;
}

// ---------------- x fp32 -> bf16 + fp8 ----------------

__global__ void convert_x_kernel(const float* __restrict__ x, bf16* __restrict__ xb,
                                 unsigned char* __restrict__ xf8) {
    int i = blockIdx.x * blockDim.x + threadIdx.x;
    int total4 = N_NODES * IN_DIM / 4;
    if (i >= total4) return;
    float4 v = ((const float4*)x)[i];
    ushort4 r;
    r.x = f2bf(v.x); r.y = f2bf(v.y); r.z = f2bf(v.z); r.w = f2bf(v.w);
    ((ushort4*)xb)[i] = r;
    ((unsigned int*)xf8)[i] = pack4_fp8(v.x, v.y, v.z, v.w);
}

// ---------------- combined weight prep ----------------

__global__ void prep_weights_kernel(const float* __restrict__ W1l, const float* __restrict__ W1r,
                                    const float* __restrict__ W2l, const float* __restrict__ W2r,
                                    const float* __restrict__ Wfc,
                                    bf16* __restrict__ w1lt, bf16* __restrict__ w1rt,
                                    bf16* __restrict__ w2lt, bf16* __restrict__ w2rt,
                                    bf16* __restrict__ wfct) {
    const int S1 = IN_DIM * HID;   // 32768
    const int S2 = HID * HID;      // 65536
    const int S3 = HID * N_CLS;    // 8192
    int i = blockIdx.x * blockDim.x + threadIdx.x;
    if (i < 2 * S1 + 2 * S2) {
        const float* W; bf16* Wt; int K, idx;
        if (i < S1)          { W = W1l; Wt = w1lt; K = IN_DIM; idx = i; }
        else if (i < 2 * S1) { W = W1r; Wt = w1rt; K = IN_DIM; idx = i - S1; }
        else if (i < 2 * S1 + S2) { W = W2l; Wt = w2lt; K = HID; idx = i - 2 * S1; }
        else                 { W = W2r; Wt = w2rt; K = HID; idx = i - 2 * S1 - S2; }
        int k = idx / HID, n = idx - k * HID;
        Wt[(size_t)n * K + k] = f2bf(W[idx]);
    } else if (i < 2 * S1 + 2 * S2 + S3) {
        int idx = i - 2 * S1 - 2 * S2;       // idx = k*32 + n
        int k = idx >> 5, n = idx & 31;
        wfct[(size_t)n * HID + k] = f2bf(Wfc[idx]);
    }
}

// ---------------- mean aggregation (fp8 gathers, sub-wave per node, x4 unroll) ----------------

__global__ void aggregate1_kernel(const unsigned char* __restrict__ xf8, const int* __restrict__ off,
                                  const int* __restrict__ csr, bf16* __restrict__ out) {
    int t = blockIdx.x * blockDim.x + threadIdx.x;
    int node = t >> 4;
    int sl = t & 15;
    if (node >= N_NODES) return;
    int s = off[node], e = off[node + 1];
    float inv = 1.0f / (float)max(e - s, 1);
    const uint2* f = (const uint2*)xf8;   // row = 16 uint2
    float a[8] = {0.f, 0.f, 0.f, 0.f, 0.f, 0.f, 0.f, 0.f};
    int i = s;
    for (; i + 4 <= e; i += 4) {
        int u0 = csr[i], u1 = csr[i + 1], u2 = csr[i + 2], u3 = csr[i + 3];
        uint2 w0 = f[(size_t)u0 * 16 + sl];
        uint2 w1 = f[(size_t)u1 * 16 + sl];
        uint2 w2 = f[(size_t)u2 * 16 + sl];
        uint2 w3 = f[(size_t)u3 * 16 + sl];
        acc8_fp8(w0, a); acc8_fp8(w1, a); acc8_fp8(w2, a); acc8_fp8(w3, a);
    }
    for (; i < e; ++i) {
        uint2 w = f[(size_t)csr[i] * 16 + sl];
        acc8_fp8(w, a);
    }
    uint4 r;
    r.x = pack2(a[0] * inv, a[1] * inv);
    r.y = pack2(a[2] * inv, a[3] * inv);
    r.z = pack2(a[4] * inv, a[5] * inv);
    r.w = pack2(a[6] * inv, a[7] * inv);
    ((uint4*)out)[(size_t)node * 16 + sl] = r;
}

__global__ void aggregate2_kernel(const unsigned char* __restrict__ hf8, const int* __restrict__ off,
                                  const int* __restrict__ csr, bf16* __restrict__ out) {
    int t = blockIdx.x * blockDim.x + threadIdx.x;
    int node = t >> 5;
    int sl = t & 31;
    if (node >= N_NODES) return;
    int s = off[node], e = off[node + 1];
    float inv = 1.0f / (float)max(e - s, 1);
    const uint2* f = (const uint2*)hf8;   // row = 32 uint2
    float a[8] = {0.f, 0.f, 0.f, 0.f, 0.f, 0.f, 0.f, 0.f};
    int i = s;
    for (; i + 4 <= e; i += 4) {
        int u0 = csr[i], u1 = csr[i + 1], u2 = csr[i + 2], u3 = csr[i + 3];
        uint2 w0 = f[(size_t)u0 * 32 + sl];
        uint2 w1 = f[(size_t)u1 * 32 + sl];
        uint2 w2 = f[(size_t)u2 * 32 + sl];
        uint2 w3 = f[(size_t)u3 * 32 + sl];
        acc8_fp8(w0, a); acc8_fp8(w1, a); acc8_fp8(w2, a); acc8_fp8(w3, a);
    }
    for (; i < e; ++i) {
        uint2 w = f[(size_t)csr[i] * 32 + sl];
        acc8_fp8(w, a);
    }
    uint4 r;
    r.x = pack2(a[0] * inv, a[1] * inv);
    r.y = pack2(a[2] * inv, a[3] * inv);
    r.z = pack2(a[4] * inv, a[5] * inv);
    r.w = pack2(a[6] * inv, a[7] * inv);
    ((uint4*)out)[(size_t)node * 32 + sl] = r;
}

// ---------------- MFMA dual GEMM: global_load_lds + 3-buffer 2-deep prefetch ----------------

#define AT_SZ 4096   // bf16 per tile buffer (128 rows x 32)

__device__ __forceinline__ void stage_tile(
    const bf16* __restrict__ Ap, const bf16* __restrict__ Wp, int K, int k0,
    int tile_m, int tile_n, int M, int wave, int lane,
    bf16* bufA, bf16* bufW) {
    // tile = 8 KB; wave w covers bytes [w*2048,(w+1)*2048) via 2 x 1KB gload_lds
#pragma unroll
    for (int is = 0; is < 2; ++is) {
        int lin = (wave * 2 + is) * 1024 + lane * 16;   // byte offset in tile
        int row = lin >> 6;                              // 64B per row
        int seg = (lin >> 4) & 3;
        int ga = min(tile_m + row, M - 1);               // clamp OOB rows (results discarded)
        gload16(Ap + (size_t)ga * K + k0 + seg * 8, (char*)bufA + (wave * 2 + is) * 1024);
        gload16(Wp + (size_t)(tile_n + row) * K + k0 + seg * 8, (char*)bufW + (wave * 2 + is) * 1024);
    }
}

__global__ __launch_bounds__(256) void gemm_dual_mfma(
    const bf16* __restrict__ A, const bf16* __restrict__ WtA, int KA,
    const bf16* __restrict__ Bm, const bf16* __restrict__ WtB, int KB,
    const float* __restrict__ bias, bf16* __restrict__ C, int M,
    float* __restrict__ psum, float* __restrict__ psq) {
    __shared__ bf16 As[3 * AT_SZ];
    __shared__ bf16 Ws[3 * AT_SZ];
    __shared__ float sred[4][64];
    __shared__ float qred[4][64];
    const int tid = threadIdx.x;
    const int lane = tid & 63;
    const int wave = tid >> 6;
    const int rw = (wave >> 1) * 64;
    const int cw = (wave & 1) * 64;
    const int lrow = lane & 15;
    const int quad = lane >> 4;
    const int tile_m = blockIdx.y * 128;
    const int tile_n = blockIdx.x * 128;

    float4v acc[4][4];
#pragma unroll
    for (int i = 0; i < 4; ++i)
#pragma unroll
        for (int j = 0; j < 4; ++j) acc[i][j] = (float4v){0.f, 0.f, 0.f, 0.f};

    const int NTA = KA >> 5;
    const int NT = NTA + (KB >> 5);
    // tile source resolver (uniform across block)
    auto tsrc = [&](int t, const bf16*& Ap, const bf16*& Wp, int& K, int& k0) {
        if (t < NTA) { Ap = A;  Wp = WtA; K = KA; k0 = t << 5; }
        else         { Ap = Bm; Wp = WtB; K = KB; k0 = (t - NTA) << 5; }
    };

    // prologue: stage tiles 0 and 1 (NT >= 4 always)
#pragma unroll
    for (int t = 0; t < 2; ++t) {
        const bf16 *Ap, *Wp; int K, k0; tsrc(t, Ap, Wp, K, k0);
        stage_tile(Ap, Wp, K, k0, tile_m, tile_n, M, wave, lane,
                   As + t * AT_SZ, Ws + t * AT_SZ);
    }

    for (int t = 0; t < NT; ++t) {
        if (t + 2 < NT) {
            const bf16 *Ap, *Wp; int K, k0; tsrc(t + 2, Ap, Wp, K, k0);
            int b = (t + 2) % 3;
            stage_tile(Ap, Wp, K, k0, tile_m, tile_n, M, wave, lane,
                       As + b * AT_SZ, Ws + b * AT_SZ);
        }
        // per-wave: 4 vmem issues per stage; keep up to 2 future tiles (8) in flight
        if (t + 2 < NT)      asm volatile("s_waitcnt vmcnt(8)" ::: "memory");
        else if (t + 1 < NT) asm volatile("s_waitcnt vmcnt(4)" ::: "memory");
        else                 asm volatile("s_waitcnt vmcnt(0)" ::: "memory");
        __builtin_amdgcn_s_barrier();
        asm volatile("" ::: "memory");

        const bf16* bA = As + (t % 3) * AT_SZ;
        const bf16* bW = Ws + (t % 3) * AT_SZ;
        short8 a[4], b[4];
#pragma unroll
        for (int i = 0; i < 4; ++i)
            a[i] = *(const short8*)(bA + (rw + i * 16 + lrow) * 32 + quad * 8);
#pragma unroll
        for (int j = 0; j < 4; ++j)
            b[j] = *(const short8*)(bW + (cw + j * 16 + lrow) * 32 + quad * 8);
#pragma unroll
        for (int i = 0; i < 4; ++i)
#pragma unroll
            for (int j = 0; j < 4; ++j)
                acc[i][j] = __builtin_amdgcn_mfma_f32_16x16x32_bf16(a[i], b[j], acc[i][j], 0, 0, 0);

        asm volatile("" ::: "memory");
        __builtin_amdgcn_s_barrier();   // protect buf (t%3) from stage at t+1 (writes (t+3)%3)
    }

    // ---- epilogue: C/D layout col=lane&15, row=quad*4+reg [verified m89] ----
    // Per-wave LDS slice (16x64 bf16 = 2 KB) -> coalesced 16B global stores.
    // j-block slot XOR'd with writer quad (= row>>2) -> conflict-free scalar writes.
    bf16* slice = As + wave * 1024;
    float bvj[4];
#pragma unroll
    for (int j = 0; j < 4; ++j) bvj[j] = bias[tile_n + cw + j * 16 + lrow];
    float cs[4] = {0.f, 0.f, 0.f, 0.f}, cq[4] = {0.f, 0.f, 0.f, 0.f};

#pragma unroll
    for (int i = 0; i < 4; ++i) {
#pragma unroll
        for (int j = 0; j < 4; ++j) {
#pragma unroll
            for (int r = 0; r < 4; ++r) {
                int row = tile_m + rw + i * 16 + quad * 4 + r;
                float v = acc[i][j][r] + bvj[j];
                if (row < M) { cs[j] += v; cq[j] += v * v; }
                slice[(quad * 4 + r) * 64 + ((j ^ quad) * 16) + lrow] = f2bf(v);
            }
        }
        __syncthreads();
        // readback: 128 uint4 chunks (16 rows x 8 chunks), lane handles 2
#pragma unroll
        for (int c = 0; c < 2; ++c) {
            int ch = lane + c * 64;
            int lr = ch >> 3, sg = ch & 7;
            int grow = tile_m + rw + i * 16 + lr;
            if (grow < M) {
                const bf16* srcp = slice + lr * 64 + (((sg >> 1) ^ (lr >> 2)) << 4) + ((sg & 1) << 3);
                uint4 v = *(const uint4*)srcp;
                *(uint4*)(C + (size_t)grow * HID + tile_n + cw + sg * 8) = v;
            }
        }
        __syncthreads();
    }

    // reduce across the 4 quads that share each (j,lrow) column
#pragma unroll
    for (int j = 0; j < 4; ++j) {
        cs[j] += __shfl_xor(cs[j], 16, 64); cs[j] += __shfl_xor(cs[j], 32, 64);
        cq[j] += __shfl_xor(cq[j], 16, 64); cq[j] += __shfl_xor(cq[j], 32, 64);
    }
    if (quad == 0) {
#pragma unroll
        for (int j = 0; j < 4; ++j) {
            sred[wave][j * 16 + lrow] = cs[j];
            qred[wave][j * 16 + lrow] = cq[j];
        }
    }
    __syncthreads();
    int bid = blockIdx.y * gridDim.x + blockIdx.x;
    if (tid < 128) {
        int grp = tid >> 6, idx = tid & 63;
        psum[(size_t)bid * 128 + tid] = sred[grp][idx] + sred[grp + 2][idx];
    } else {
        int t = tid - 128;
        int grp = t >> 6, idx = t & 63;
        psq[(size_t)bid * 128 + t] = qred[grp][idx] + qred[grp + 2][idx];
    }
}

// reduce per-block partials -> stats[0..255]=sum, stats[256..511]=sumsq
__global__ void bn_finalize_kernel(const float* __restrict__ psum, const float* __restrict__ psq,
                                   float* __restrict__ stats, int nby) {
    const float* src = blockIdx.y ? psq : psum;
    int c = threadIdx.x;           // 0..255 = global column
    int bx = c >> 7, cl = c & 127;
    int per = (nby + gridDim.x - 1) / gridDim.x;
    int b0 = blockIdx.x * per, b1 = min(b0 + per, nby);
    float s = 0.f;
    for (int by = b0; by < b1; ++by) s += src[(size_t)(by * 2 + bx) * 128 + cl];
    atomicAdd(&stats[blockIdx.y * HID + c], s);
}

// ---------------- BN apply + ReLU (layer 1; also emits fp8 copy for gather) ----------------

__global__ void bn_apply_relu_kernel(bf16* __restrict__ h, unsigned char* __restrict__ hf8,
                                     const float* __restrict__ stats,
                                     const float* __restrict__ g, const float* __restrict__ be,
                                     int M) {
    int i4 = blockIdx.x * blockDim.x + threadIdx.x;
    int total4 = M * (HID / 4);
    if (i4 >= total4) return;
    int col4 = i4 & (HID / 4 - 1);
    ushort4 v = ((const ushort4*)h)[i4];
    float invN = 1.0f / (float)M;
    float o[4] = {bf2f(v.x), bf2f(v.y), bf2f(v.z), bf2f(v.w)};
#pragma unroll
    for (int j = 0; j < 4; ++j) {
        int col = col4 * 4 + j;
        float mu = stats[col] * invN;
        float var = stats[HID + col] * invN - mu * mu;
        float sc = rsqrtf(var + BN_EPS) * g[col];
        float val = (o[j] - mu) * sc + be[col];
        o[j] = val > 0.f ? val : 0.f;
    }
    ushort4 r;
    r.x = f2bf(o[0]); r.y = f2bf(o[1]); r.z = f2bf(o[2]); r.w = f2bf(o[3]);
    ((ushort4*)h)[i4] = r;
    ((unsigned int*)hf8)[i4] = pack4_fp8(o[0], o[1], o[2], o[3]);
}

// ---------------- final FC (MFMA) with fused BN2+ReLU ----------------

#define BSTR 264   // 256 + 8 pad

__global__ __launch_bounds__(256) void fc_bn_mfma_kernel(
    const bf16* __restrict__ h, const float* __restrict__ stats,
    const float* __restrict__ g, const float* __restrict__ be,
    const bf16* __restrict__ WfcT, const float* __restrict__ bfc,
    float* __restrict__ out, int M) {
    __shared__ bf16 Bs[32 * BSTR];
    __shared__ float sc_s[HID], sh_s[HID];
    int tid = threadIdx.x;
    for (int i = tid; i < 32 * 32; i += 256) {   // 1024 16B chunks
        int rrow = i >> 5, seg = i & 31;
        *(uint4*)(Bs + rrow * BSTR + seg * 8) = *(const uint4*)(WfcT + (size_t)rrow * HID + seg * 8);
    }
    {
        float invN = 1.0f / (float)M;
        float mu = stats[tid] * invN;
        float var = stats[HID + tid] * invN - mu * mu;
        float s = rsqrtf(var + BN_EPS) * g[tid];
        sc_s[tid] = s;
        sh_s[tid] = be[tid] - mu * s;
    }
    __syncthreads();
    int wave = tid >> 6, lane = tid & 63, lrow = lane & 15, quad = lane >> 4;
    int row = blockIdx.x * 64 + wave * 16 + lrow;
    const bf16* hrow = h + (size_t)row * HID;
    float4v acc0 = {0.f, 0.f, 0.f, 0.f}, acc1 = {0.f, 0.f, 0.f, 0.f};
#pragma unroll
    for (int ks = 0; ks < 8; ++ks) {
        int k0 = ks * 32 + quad * 8;
        uint4 av = {0u, 0u, 0u, 0u};
        if (row < M) av = *(const uint4*)(hrow + k0);
        union { unsigned int u[4]; short8 s8; } cvt;
        unsigned int* avp = (unsigned int*)&av;
#pragma unroll
        for (int t = 0; t < 4; ++t) {
            int k = k0 + t * 2;
            float v0 = blo(avp[t]) * sc_s[k] + sh_s[k];
            float v1 = bhi(avp[t]) * sc_s[k + 1] + sh_s[k + 1];
            v0 = v0 > 0.f ? v0 : 0.f;
            v1 = v1 > 0.f ? v1 : 0.f;
            cvt.u[t] = pack2(v0, v1);
        }
        short8 b0 = *(const short8*)(Bs + lrow * BSTR + k0);
        short8 b1 = *(const short8*)(Bs + (16 + lrow) * BSTR + k0);
        acc0 = __builtin_amdgcn_mfma_f32_16x16x32_bf16(cvt.s8, b0, acc0, 0, 0, 0);
        acc1 = __builtin_amdgcn_mfma_f32_16x16x32_bf16(cvt.s8, b1, acc1, 0, 0, 0);
    }
    int orow = blockIdx.x * 64 + wave * 16 + quad * 4;
    float bv0 = bfc[lrow], bv1 = bfc[16 + lrow];
#pragma unroll
    for (int r = 0; r < 4; ++r) {
        int rr = orow + r;
        if (rr < M) {
            out[(size_t)rr * N_CLS + lrow] = acc0[r] + bv0;
            out[(size_t)rr * N_CLS + 16 + lrow] = acc1[r] + bv1;
        }
    }
}

// ---------------- launch ----------------

extern "C" void kernel_launch(void* const* d_in, const int* in_sizes, int n_in,
                              void* d_out, int out_size, void* d_ws, size_t ws_size,
                              hipStream_t stream) {
    const float* x   = (const float*)d_in[0];
    const int* esrc  = (const int*)d_in[1];
    const int* edst  = (const int*)d_in[2];
    const float* W1l = (const float*)d_in[3];
    const float* b1  = (const float*)d_in[4];
    const float* W1r = (const float*)d_in[5];
    const float* g1  = (const float*)d_in[6];
    const float* be1 = (const float*)d_in[7];
    const float* W2l = (const float*)d_in[8];
    const float* b2  = (const float*)d_in[9];
    const float* W2r = (const float*)d_in[10];
    const float* g2  = (const float*)d_in[11];
    const float* be2 = (const float*)d_in[12];
    const float* Wfc = (const float*)d_in[13];
    const float* bfc = (const float*)d_in[14];
    float* out = (float*)d_out;

    char* ws = (char*)d_ws;
    size_t o = 0;
    auto carve = [&](size_t bytes) {
        char* p = ws + o;
        o = (o + bytes + 255) & ~(size_t)255;
        return p;
    };
    int*   off    = (int*)carve((N_NODES + 1) * sizeof(int));
    int*   cursor = (int*)carve(N_NODES * sizeof(int));
    int*   csr    = (int*)carve(N_EDGES * sizeof(int));
    int*   bsums  = (int*)carve(SCAN_NB * sizeof(int));
    int*   boffs  = (int*)carve(SCAN_NB * sizeof(int));
    int*   bcur   = (int*)carve(NBUCK * sizeof(int));
    float* stats1 = (float*)carve(2 * HID * sizeof(float));
    float* stats2 = (float*)carve(2 * HID * sizeof(float));
    float* psum   = (float*)carve((size_t)GEMM_NB * 128 * sizeof(float));
    float* psq    = (float*)carve((size_t)GEMM_NB * 128 * sizeof(float));
    bf16*  w1lt   = (bf16*)carve((size_t)IN_DIM * HID * sizeof(bf16));
    bf16*  w1rt   = (bf16*)carve((size_t)IN_DIM * HID * sizeof(bf16));
    bf16*  w2lt   = (bf16*)carve((size_t)HID * HID * sizeof(bf16));
    bf16*  w2rt   = (bf16*)carve((size_t)HID * HID * sizeof(bf16));
    bf16*  wfct   = (bf16*)carve((size_t)N_CLS * HID * sizeof(bf16));
    bf16*  agg    = (bf16*)carve((size_t)N_NODES * HID * sizeof(bf16));
    bf16*  h1     = (bf16*)carve((size_t)N_NODES * HID * sizeof(bf16));
    bf16*  h2     = (bf16*)carve((size_t)N_NODES * HID * sizeof(bf16));
    // overlays inside the h2 region (lifetimes stream-ordered disjoint):
    //   xb  = h2[0   : 25.6MB]  bf16 x   — dead after gemm1
    //   xf8 = h2[25.6: 38.4MB]  fp8 x    — dead after aggregate1
    //   h1f8= h2[0   : 25.6MB]  fp8 bn(h1) — written post-gemm1, read by aggregate2,
    //                                        then gemm2 overwrites h2
    bf16*          xb   = h2;
    unsigned char* xf8  = (unsigned char*)h2 + (size_t)N_NODES * IN_DIM * sizeof(bf16);
    unsigned char* h1f8 = (unsigned char*)h2;
    // overlay inside the agg region (dead until aggregate1 writes it):
    //   bstore = 16 buckets x 112K edges x 8B = 14.3 MB < 51.2 MB
    int2*          bstore = (int2*)agg;
    // overlay inside the h1 region (dead until gemm1 writes it):
    //   partial = HSUBS x N_NODES ints = 6.4 MB < 51.2 MB
    int*           partial = (int*)h1;

    if (o > ws_size) return;  // clean fail instead of fault

    hipMemsetAsync(bcur, 0, NBUCK * sizeof(int), stream);
    hipMemsetAsync(stats1, 0, 2 * HID * sizeof(float), stream);
    hipMemsetAsync(stats2, 0, 2 * HID * sizeof(float), stream);

    // CSR build: bucket scatter (no global atomics) -> LDS-privatized degree hist ->
    // scans -> per-bucket fine scatter
    bucket_scatter_kernel<<<PASSA_NB, 256, 0, stream>>>(esrc, edst, bcur, bstore);
    bucket_hist_kernel<<<NBUCK * HSUBS, 256, 0, stream>>>(bstore, bcur, partial);
    scan1_kernel<<<SCAN_NB, 256, 0, stream>>>(partial, cursor, bsums);   // cursor <- counts
    scan2_kernel<<<1, 128, 0, stream>>>(bsums, boffs);
    scan3_kernel<<<SCAN_NB, 256, 0, stream>>>(cursor, boffs, off);
    hipMemsetAsync(cursor, 0, N_NODES * sizeof(int), stream);
    fill_bucket_kernel<<<NBUCK * FILL_SUBS, 256, 0, stream>>>(bstore, bcur, off, cursor, csr);

    // prep: x -> bf16 + fp8, all weights -> bf16 transposed
    convert_x_kernel<<<(N_NODES * IN_DIM / 4 + 255) / 256, 256, 0, stream>>>(x, xb, xf8);
    {
        int total = 2 * IN_DIM * HID + 2 * HID * HID + HID * N_CLS;
        prep_weights_kernel<<<(total + 255) / 256, 256, 0, stream>>>(
            W1l, W1r, W2l, W2r, Wfc, w1lt, w1rt, w2lt, w2rt, wfct);
    }

    const dim3 ggrid(HID / 128, GEMM_NBY);

    // ---- layer 1 ----
    aggregate1_kernel<<<(N_NODES * 16 + 255) / 256, 256, 0, stream>>>(xf8, off, csr, agg);
    gemm_dual_mfma<<<ggrid, 256, 0, stream>>>(
        agg, w1lt, IN_DIM, xb, w1rt, IN_DIM, b1, h1, N_NODES, psum, psq);
    bn_finalize_kernel<<<dim3(8, 2), 256, 0, stream>>>(psum, psq, stats1, GEMM_NBY);
    {
        int total4 = N_NODES * (HID / 4);
        bn_apply_relu_kernel<<<(total4 + 255) / 256, 256, 0, stream>>>(h1, h1f8, stats1, g1, be1, N_NODES);
    }

    // ---- layer 2 ----
    aggregate2_kernel<<<(N_NODES * 32 + 255) / 256, 256, 0, stream>>>(h1f8, off, csr, agg);
    gemm_dual_mfma<<<ggrid, 256, 0, stream>>>(
        agg, w2lt, HID, h1, w2rt, HID, b2, h2, N_NODES, psum, psq);
    bn_finalize_kernel<<<dim3(8, 2), 256, 0, stream>>>(psum, psq, stats2, GEMM_NBY);

    // ---- final FC (MFMA) with fused BN2+ReLU ----
    fc_bn_mfma_kernel<<<(N_NODES + 63) / 64, 256, 0, stream>>>(
        h2, stats2, g2, be2, wfct, bfc, out, N_NODES);
}

// Round 4
// 463.272 us; speedup vs baseline: 1.2442x; 1.1057x over previous
//
#include <hip/hip_runtime.h>

#define N_NODES 100000
#define N_EDGES 1600000
#define IN_DIM 128
#define HID 256
#define N_CLS 32
#define BN_EPS 1e-5f

#define SCAN_CHUNK 1024
#define SCAN_NB ((N_NODES + SCAN_CHUNK - 1) / SCAN_CHUNK)   // 98
#define GEMM_NBY ((N_NODES + 127) / 128)                    // 782
#define GEMM_NB (GEMM_NBY * 2)                              // 1564 blocks (2 n-tiles)

// ---- bucketed CSR fill parameters ----
#define NBUCK 16
#define BUCK_NODES 6250        // 16 * 6250 = 100000 exactly
#define BUCK_CAP 112000        // expected 100K/bucket, sd ~306 -> huge margin
#define PASSA_CHUNK 2048       // edges staged per block (16 KB LDS)
#define PASSA_NB ((N_EDGES + PASSA_CHUNK - 1) / PASSA_CHUNK)  // 782
#define HSUBS 32               // histogram/fill slices per bucket

typedef unsigned short bf16;
typedef __attribute__((ext_vector_type(8))) short short8;
typedef __attribute__((ext_vector_type(4))) float float4v;
typedef __attribute__((ext_vector_type(2))) float floatx2;

__device__ __forceinline__ float bf2f(bf16 h) {
    return __uint_as_float(((unsigned int)h) << 16);
}
__device__ __forceinline__ bf16 f2bf(float f) {
    unsigned int u = __float_as_uint(f);
    u += 0x7FFFu + ((u >> 16) & 1u);   // round-to-nearest-even
    return (bf16)(u >> 16);
}
__device__ __forceinline__ float blo(unsigned int u) { return __uint_as_float(u << 16); }
__device__ __forceinline__ float bhi(unsigned int u) { return __uint_as_float(u & 0xFFFF0000u); }
__device__ __forceinline__ unsigned int pack2(float lo, float hi) {
    return (unsigned int)f2bf(lo) | ((unsigned int)f2bf(hi) << 16);
}

// fp8 (OCP e4m3 on gfx950) hardware conversions
__device__ __forceinline__ void acc8_fp8(uint2 w, float* a) {
    floatx2 f0 = __builtin_amdgcn_cvt_pk_f32_fp8(w.x, false);
    floatx2 f1 = __builtin_amdgcn_cvt_pk_f32_fp8(w.x, true);
    floatx2 f2 = __builtin_amdgcn_cvt_pk_f32_fp8(w.y, false);
    floatx2 f3 = __builtin_amdgcn_cvt_pk_f32_fp8(w.y, true);
    a[0] += f0.x; a[1] += f0.y; a[2] += f1.x; a[3] += f1.y;
    a[4] += f2.x; a[5] += f2.y; a[6] += f3.x; a[7] += f3.y;
}
__device__ __forceinline__ unsigned int pack4_fp8(float a, float b, float c, float d) {
    int p = 0;
    p = __builtin_amdgcn_cvt_pk_fp8_f32(a, b, p, false);
    p = __builtin_amdgcn_cvt_pk_fp8_f32(c, d, p, true);
    return (unsigned int)p;
}

// async global->LDS, 16B per lane, wave-uniform LDS base + lane*16
__device__ __forceinline__ void gload16(const void* g, void* l) {
    __builtin_amdgcn_global_load_lds(
        (const __attribute__((address_space(1))) void*)g,
        (__attribute__((address_space(3))) void*)l, 16, 0, 0);
}

// ---------------- CSR build: pass A — bucket scatter (no global atomics) ----------------
// Streams edges once. Per block: LDS-stage 2048 (src,dst) pairs grouped by dst-bucket,
// reserve per-bucket global ranges with one atomic per bucket, write contiguous runs.

__global__ __launch_bounds__(256) void bucket_scatter_kernel(
    const int* __restrict__ esrc, const int* __restrict__ edst,
    int* __restrict__ bcur, int2* __restrict__ bstore) {
    __shared__ int lhist[NBUCK], lbase[NBUCK], gbase[NBUCK], lcur[NBUCK];
    __shared__ int2 stage[PASSA_CHUNK];    // 16 KB
    const int tid = threadIdx.x;
    if (tid < NBUCK) lhist[tid] = 0;
    __syncthreads();

    const int base = blockIdx.x * PASSA_CHUNK;
    const int nedge = min(PASSA_CHUNK, N_EDGES - base);
    // N_EDGES % 8 == 0, so each thread's 8-edge chunk is all-or-nothing.
    const bool act = (tid * 8) < nedge;
    int s[8], d[8], bk[8];
    if (act) {
        const int4* s4 = (const int4*)(esrc + base + tid * 8);
        const int4* d4 = (const int4*)(edst + base + tid * 8);
#pragma unroll
        for (int t = 0; t < 2; ++t) {
            int4 sv = s4[t], dv = d4[t];
            s[t * 4 + 0] = sv.x; s[t * 4 + 1] = sv.y; s[t * 4 + 2] = sv.z; s[t * 4 + 3] = sv.w;
            d[t * 4 + 0] = dv.x; d[t * 4 + 1] = dv.y; d[t * 4 + 2] = dv.z; d[t * 4 + 3] = dv.w;
        }
#pragma unroll
        for (int u = 0; u < 8; ++u) {
            bk[u] = (int)((unsigned)d[u] / BUCK_NODES);
            atomicAdd(&lhist[bk[u]], 1);        // block-local bucket counts (LDS only)
        }
    }
    __syncthreads();
    if (tid == 0) {
        int run = 0;
#pragma unroll
        for (int b = 0; b < NBUCK; ++b) { lbase[b] = run; lcur[b] = run; run += lhist[b]; }
    }
    if (tid < NBUCK) gbase[tid] = atomicAdd(&bcur[tid], lhist[tid]);
    __syncthreads();
    if (act) {
#pragma unroll
        for (int u = 0; u < 8; ++u) {
            int p = atomicAdd(&lcur[bk[u]], 1);
            stage[p] = make_int2(s[u], d[u]);
        }
    }
    __syncthreads();
    // write out: LDS position p -> global bstore[b*CAP + gbase[b] + (p - lbase[b])]
    for (int p = tid; p < nedge; p += 256) {
        int2 e = stage[p];
        int b = (int)((unsigned)e.y / BUCK_NODES);
        int gp = gbase[b] + (p - lbase[b]);
        if (gp < BUCK_CAP) bstore[(size_t)b * BUCK_CAP + gp] = e;
    }
}

// ---------------- CSR build: per-(bucket,slice) degree histogram (LDS-privatized) ----------------
// Bucket spans 6250 nodes = 25 KB -> full histogram fits in LDS. HSUBS slices per bucket
// for parallelism; partial[s][node] streamed out coalesced, no global atomics at all.

__global__ __launch_bounds__(256) void bucket_hist_kernel(
    const int2* __restrict__ bstore, const int* __restrict__ bcnt,
    int* __restrict__ partial) {
    __shared__ int hist[BUCK_NODES];   // 25000 B
    const int bk = blockIdx.x & (NBUCK - 1);
    const int sl = blockIdx.x >> 4;
    for (int i = threadIdx.x; i < BUCK_NODES; i += 256) hist[i] = 0;
    __syncthreads();
    const int n = bcnt[bk];
    const int per = (n + HSUBS - 1) / HSUBS;
    const int i0 = sl * per, i1 = min(i0 + per, n);
    const int2* ep = bstore + (size_t)bk * BUCK_CAP;
    const int nbase = bk * BUCK_NODES;
    for (int i = i0 + threadIdx.x; i < i1; i += 256) {
        atomicAdd(&hist[ep[i].y - nbase], 1);
    }
    __syncthreads();
    int* dst = partial + (size_t)sl * N_NODES + nbase;
    for (int i = threadIdx.x; i < BUCK_NODES; i += 256) dst[i] = hist[i];
}

// ---------------- CSR build: pass B — per-bucket deterministic fill (LDS atomics only) ----------------
// Block = (bucket, slice), slice ranges IDENTICAL to bucket_hist. base[] = off[n] +
// exclusive-prefix-over-slices (from scan1's in-place rewrite of partial). Each edge
// claims a unique csr slot via an LDS atomic -> zero global atomics, zero HBM RMW.

__global__ __launch_bounds__(256) void fill_bucket_kernel(
    const int2* __restrict__ bstore, const int* __restrict__ bcnt,
    const int* __restrict__ off, const int* __restrict__ partial,
    int* __restrict__ csr) {
    __shared__ int basec[BUCK_NODES];   // 25000 B
    const int bk = blockIdx.x & (NBUCK - 1);
    const int sl = blockIdx.x >> 4;
    const int nbase = bk * BUCK_NODES;
    const int* prow = partial + (size_t)sl * N_NODES + nbase;
    const int* orow = off + nbase;
    for (int i = threadIdx.x; i < BUCK_NODES; i += 256) basec[i] = orow[i] + prow[i];
    __syncthreads();
    const int n = bcnt[bk];
    const int per = (n + HSUBS - 1) / HSUBS;
    const int i0 = sl * per, i1 = min(i0 + per, n);
    const int2* ep = bstore + (size_t)bk * BUCK_CAP;
    for (int i = i0 + threadIdx.x; i < i1; i += 256) {
        int2 e = ep[i];
        int p = atomicAdd(&basec[e.y - nbase], 1);
        csr[p] = e.x;
    }
}

// ---------------- prefix scans ----------------
// scan1 folds the HSUBS partial histograms into counts AND rewrites partial in place
// as the exclusive prefix across slices (per node), for the deterministic fill.

__global__ void scan1_kernel(int* __restrict__ partial, int* __restrict__ counts,
                             int* __restrict__ bsums) {
    __shared__ int wsum[4];
    int base = blockIdx.x * SCAN_CHUNK + threadIdx.x * 4;
    int c0 = 0, c1 = 0, c2 = 0, c3 = 0;
    if (base + 4 <= N_NODES) {
#pragma unroll
        for (int sl = 0; sl < HSUBS; ++sl) {
            int* p = partial + (size_t)sl * N_NODES + base;
            int4 v = *(const int4*)p;
            int4 w; w.x = c0; w.y = c1; w.z = c2; w.w = c3;
            *(int4*)p = w;                     // exclusive prefix (before adding v)
            c0 += v.x; c1 += v.y; c2 += v.z; c3 += v.w;
        }
        int4 w; w.x = c0; w.y = c1; w.z = c2; w.w = c3;
        *(int4*)(counts + base) = w;
    } else {
        for (int j = 0; j < 4; ++j) {
            if (base + j < N_NODES) {
                int c = 0;
                for (int sl = 0; sl < HSUBS; ++sl) {
                    int* p = partial + (size_t)sl * N_NODES + base + j;
                    int v = *p; *p = c; c += v;
                }
                counts[base + j] = c;
                if (j == 0) c0 = c; else if (j == 1) c1 = c; else if (j == 2) c2 = c; else c3 = c;
            }
        }
    }
    int s = c0 + c1 + c2 + c3;
    for (int d = 32; d > 0; d >>= 1) s += __shfl_down(s, d, 64);
    if ((threadIdx.x & 63) == 0) wsum[threadIdx.x >> 6] = s;
    __syncthreads();
    if (threadIdx.x == 0) bsums[blockIdx.x] = wsum[0] + wsum[1] + wsum[2] + wsum[3];
}

__global__ void scan2_kernel(const int* __restrict__ bsums, int* __restrict__ boffs) {
    __shared__ int sh[128];
    int i = threadIdx.x;
    int v = (i < SCAN_NB) ? bsums[i] : 0;
    sh[i] = v;
    __syncthreads();
    for (int d = 1; d < 128; d <<= 1) {
        int t = (i >= d) ? sh[i - d] : 0;
        __syncthreads();
        sh[i] += t;
        __syncthreads();
    }
    if (i < SCAN_NB) boffs[i] = sh[i] - v;
}

__global__ void scan3_kernel(const int* __restrict__ counts, const int* __restrict__ boffs,
                             int* __restrict__ off) {
    __shared__ int sh[256];
    int tid = threadIdx.x;
    int base = blockIdx.x * SCAN_CHUNK + tid * 4;
    int c0 = 0, c1 = 0, c2 = 0, c3 = 0;
    if (base + 4 <= N_NODES) {
        int4 v = *(const int4*)(counts + base);
        c0 = v.x; c1 = v.y; c2 = v.z; c3 = v.w;
    } else {
        if (base + 0 < N_NODES) c0 = counts[base + 0];
        if (base + 1 < N_NODES) c1 = counts[base + 1];
        if (base + 2 < N_NODES) c2 = counts[base + 2];
        if (base + 3 < N_NODES) c3 = counts[base + 3];
    }
    int ts = c0 + c1 + c2 + c3;
    sh[tid] = ts;
    __syncthreads();
    for (int d = 1; d < 256; d <<= 1) {
        int t = (tid >= d) ? sh[tid - d] : 0;
        __syncthreads();
        sh[tid] += t;
        __syncthreads();
    }
    int run = boffs[blockIdx.x] + sh[tid] - ts;
    if (base + 0 < N_NODES) off[base + 0] = run; run += c0;
    if (base + 1 < N_NODES) off[base + 1] = run; run += c1;
    if (base + 2 < N_NODES) off[base + 2] = run; run += c2;
    if (base + 3 < N_NODES) off[base + 3] = run;
    if (blockIdx.x == 0 && tid == 0) off[N_NODES] = N_EDGES;
}

// ---------------- x fp32 -> bf16 + fp8 ----------------

__global__ void convert_x_kernel(const float* __restrict__ x, bf16* __restrict__ xb,
                                 unsigned char* __restrict__ xf8) {
    int i = blockIdx.x * blockDim.x + threadIdx.x;
    int total4 = N_NODES * IN_DIM / 4;
    if (i >= total4) return;
    float4 v = ((const float4*)x)[i];
    ushort4 r;
    r.x = f2bf(v.x); r.y = f2bf(v.y); r.z = f2bf(v.z); r.w = f2bf(v.w);
    ((ushort4*)xb)[i] = r;
    ((unsigned int*)xf8)[i] = pack4_fp8(v.x, v.y, v.z, v.w);
}

// ---------------- combined weight prep ----------------

__global__ void prep_weights_kernel(const float* __restrict__ W1l, const float* __restrict__ W1r,
                                    const float* __restrict__ W2l, const float* __restrict__ W2r,
                                    const float* __restrict__ Wfc,
                                    bf16* __restrict__ w1lt, bf16* __restrict__ w1rt,
                                    bf16* __restrict__ w2lt, bf16* __restrict__ w2rt,
                                    bf16* __restrict__ wfct) {
    const int S1 = IN_DIM * HID;   // 32768
    const int S2 = HID * HID;      // 65536
    const int S3 = HID * N_CLS;    // 8192
    int i = blockIdx.x * blockDim.x + threadIdx.x;
    if (i < 2 * S1 + 2 * S2) {
        const float* W; bf16* Wt; int K, idx;
        if (i < S1)          { W = W1l; Wt = w1lt; K = IN_DIM; idx = i; }
        else if (i < 2 * S1) { W = W1r; Wt = w1rt; K = IN_DIM; idx = i - S1; }
        else if (i < 2 * S1 + S2) { W = W2l; Wt = w2lt; K = HID; idx = i - 2 * S1; }
        else                 { W = W2r; Wt = w2rt; K = HID; idx = i - 2 * S1 - S2; }
        int k = idx / HID, n = idx - k * HID;
        Wt[(size_t)n * K + k] = f2bf(W[idx]);
    } else if (i < 2 * S1 + 2 * S2 + S3) {
        int idx = i - 2 * S1 - 2 * S2;       // idx = k*32 + n
        int k = idx >> 5, n = idx & 31;
        wfct[(size_t)n * HID + k] = f2bf(Wfc[idx]);
    }
}

// ---------------- mean aggregation (fp8 gathers, sub-wave per node, x4 unroll) ----------------

__global__ void aggregate1_kernel(const unsigned char* __restrict__ xf8, const int* __restrict__ off,
                                  const int* __restrict__ csr, bf16* __restrict__ out) {
    int t = blockIdx.x * blockDim.x + threadIdx.x;
    int node = t >> 4;
    int sl = t & 15;
    if (node >= N_NODES) return;
    int s = off[node], e = off[node + 1];
    float inv = 1.0f / (float)max(e - s, 1);
    const uint2* f = (const uint2*)xf8;   // row = 16 uint2
    float a[8] = {0.f, 0.f, 0.f, 0.f, 0.f, 0.f, 0.f, 0.f};
    int i = s;
    for (; i + 4 <= e; i += 4) {
        int u0 = csr[i], u1 = csr[i + 1], u2 = csr[i + 2], u3 = csr[i + 3];
        uint2 w0 = f[(size_t)u0 * 16 + sl];
        uint2 w1 = f[(size_t)u1 * 16 + sl];
        uint2 w2 = f[(size_t)u2 * 16 + sl];
        uint2 w3 = f[(size_t)u3 * 16 + sl];
        acc8_fp8(w0, a); acc8_fp8(w1, a); acc8_fp8(w2, a); acc8_fp8(w3, a);
    }
    for (; i < e; ++i) {
        uint2 w = f[(size_t)csr[i] * 16 + sl];
        acc8_fp8(w, a);
    }
    uint4 r;
    r.x = pack2(a[0] * inv, a[1] * inv);
    r.y = pack2(a[2] * inv, a[3] * inv);
    r.z = pack2(a[4] * inv, a[5] * inv);
    r.w = pack2(a[6] * inv, a[7] * inv);
    ((uint4*)out)[(size_t)node * 16 + sl] = r;
}

__global__ void aggregate2_kernel(const unsigned char* __restrict__ hf8, const int* __restrict__ off,
                                  const int* __restrict__ csr, bf16* __restrict__ out) {
    int t = blockIdx.x * blockDim.x + threadIdx.x;
    int node = t >> 5;
    int sl = t & 31;
    if (node >= N_NODES) return;
    int s = off[node], e = off[node + 1];
    float inv = 1.0f / (float)max(e - s, 1);
    const uint2* f = (const uint2*)hf8;   // row = 32 uint2
    float a[8] = {0.f, 0.f, 0.f, 0.f, 0.f, 0.f, 0.f, 0.f};
    int i = s;
    for (; i + 4 <= e; i += 4) {
        int u0 = csr[i], u1 = csr[i + 1], u2 = csr[i + 2], u3 = csr[i + 3];
        uint2 w0 = f[(size_t)u0 * 32 + sl];
        uint2 w1 = f[(size_t)u1 * 32 + sl];
        uint2 w2 = f[(size_t)u2 * 32 + sl];
        uint2 w3 = f[(size_t)u3 * 32 + sl];
        acc8_fp8(w0, a); acc8_fp8(w1, a); acc8_fp8(w2, a); acc8_fp8(w3, a);
    }
    for (; i < e; ++i) {
        uint2 w = f[(size_t)csr[i] * 32 + sl];
        acc8_fp8(w, a);
    }
    uint4 r;
    r.x = pack2(a[0] * inv, a[1] * inv);
    r.y = pack2(a[2] * inv, a[3] * inv);
    r.z = pack2(a[4] * inv, a[5] * inv);
    r.w = pack2(a[6] * inv, a[7] * inv);
    ((uint4*)out)[(size_t)node * 32 + sl] = r;
}

// ---------------- MFMA dual GEMM: global_load_lds + 3-buffer 2-deep prefetch ----------------

#define AT_SZ 4096   // bf16 per tile buffer (128 rows x 32)

__device__ __forceinline__ void stage_tile(
    const bf16* __restrict__ Ap, const bf16* __restrict__ Wp, int K, int k0,
    int tile_m, int tile_n, int M, int wave, int lane,
    bf16* bufA, bf16* bufW) {
    // tile = 8 KB; wave w covers bytes [w*2048,(w+1)*2048) via 2 x 1KB gload_lds
#pragma unroll
    for (int is = 0; is < 2; ++is) {
        int lin = (wave * 2 + is) * 1024 + lane * 16;   // byte offset in tile
        int row = lin >> 6;                              // 64B per row
        int seg = (lin >> 4) & 3;
        int ga = min(tile_m + row, M - 1);               // clamp OOB rows (results discarded)
        gload16(Ap + (size_t)ga * K + k0 + seg * 8, (char*)bufA + (wave * 2 + is) * 1024);
        gload16(Wp + (size_t)(tile_n + row) * K + k0 + seg * 8, (char*)bufW + (wave * 2 + is) * 1024);
    }
}

__global__ __launch_bounds__(256) void gemm_dual_mfma(
    const bf16* __restrict__ A, const bf16* __restrict__ WtA, int KA,
    const bf16* __restrict__ Bm, const bf16* __restrict__ WtB, int KB,
    const float* __restrict__ bias, bf16* __restrict__ C, int M,
    float* __restrict__ psum, float* __restrict__ psq) {
    __shared__ bf16 As[3 * AT_SZ];
    __shared__ bf16 Ws[3 * AT_SZ];
    __shared__ float sred[4][64];
    __shared__ float qred[4][64];
    const int tid = threadIdx.x;
    const int lane = tid & 63;
    const int wave = tid >> 6;
    const int rw = (wave >> 1) * 64;
    const int cw = (wave & 1) * 64;
    const int lrow = lane & 15;
    const int quad = lane >> 4;
    const int tile_m = blockIdx.y * 128;
    const int tile_n = blockIdx.x * 128;

    float4v acc[4][4];
#pragma unroll
    for (int i = 0; i < 4; ++i)
#pragma unroll
        for (int j = 0; j < 4; ++j) acc[i][j] = (float4v){0.f, 0.f, 0.f, 0.f};

    const int NTA = KA >> 5;
    const int NT = NTA + (KB >> 5);
    // tile source resolver (uniform across block)
    auto tsrc = [&](int t, const bf16*& Ap, const bf16*& Wp, int& K, int& k0) {
        if (t < NTA) { Ap = A;  Wp = WtA; K = KA; k0 = t << 5; }
        else         { Ap = Bm; Wp = WtB; K = KB; k0 = (t - NTA) << 5; }
    };

    // prologue: stage tiles 0 and 1 (NT >= 4 always)
#pragma unroll
    for (int t = 0; t < 2; ++t) {
        const bf16 *Ap, *Wp; int K, k0; tsrc(t, Ap, Wp, K, k0);
        stage_tile(Ap, Wp, K, k0, tile_m, tile_n, M, wave, lane,
                   As + t * AT_SZ, Ws + t * AT_SZ);
    }

    for (int t = 0; t < NT; ++t) {
        if (t + 2 < NT) {
            const bf16 *Ap, *Wp; int K, k0; tsrc(t + 2, Ap, Wp, K, k0);
            int b = (t + 2) % 3;
            stage_tile(Ap, Wp, K, k0, tile_m, tile_n, M, wave, lane,
                       As + b * AT_SZ, Ws + b * AT_SZ);
        }
        // per-wave: 4 vmem issues per stage; keep up to 2 future tiles (8) in flight
        if (t + 2 < NT)      asm volatile("s_waitcnt vmcnt(8)" ::: "memory");
        else if (t + 1 < NT) asm volatile("s_waitcnt vmcnt(4)" ::: "memory");
        else                 asm volatile("s_waitcnt vmcnt(0)" ::: "memory");
        __builtin_amdgcn_s_barrier();
        asm volatile("" ::: "memory");

        const bf16* bA = As + (t % 3) * AT_SZ;
        const bf16* bW = Ws + (t % 3) * AT_SZ;
        short8 a[4], b[4];
#pragma unroll
        for (int i = 0; i < 4; ++i)
            a[i] = *(const short8*)(bA + (rw + i * 16 + lrow) * 32 + quad * 8);
#pragma unroll
        for (int j = 0; j < 4; ++j)
            b[j] = *(const short8*)(bW + (cw + j * 16 + lrow) * 32 + quad * 8);
#pragma unroll
        for (int i = 0; i < 4; ++i)
#pragma unroll
            for (int j = 0; j < 4; ++j)
                acc[i][j] = __builtin_amdgcn_mfma_f32_16x16x32_bf16(a[i], b[j], acc[i][j], 0, 0, 0);

        asm volatile("" ::: "memory");
        __builtin_amdgcn_s_barrier();   // protect buf (t%3) from stage at t+1 (writes (t+3)%3)
    }

    // ---- epilogue: C/D layout col=lane&15, row=quad*4+reg [verified m89] ----
    // Per-wave LDS slice (16x64 bf16 = 2 KB) -> coalesced 16B global stores.
    // j-block slot XOR'd with writer quad (= row>>2) -> conflict-free scalar writes.
    bf16* slice = As + wave * 1024;
    float bvj[4];
#pragma unroll
    for (int j = 0; j < 4; ++j) bvj[j] = bias[tile_n + cw + j * 16 + lrow];
    float cs[4] = {0.f, 0.f, 0.f, 0.f}, cq[4] = {0.f, 0.f, 0.f, 0.f};

#pragma unroll
    for (int i = 0; i < 4; ++i) {
#pragma unroll
        for (int j = 0; j < 4; ++j) {
#pragma unroll
            for (int r = 0; r < 4; ++r) {
                int row = tile_m + rw + i * 16 + quad * 4 + r;
                float v = acc[i][j][r] + bvj[j];
                if (row < M) { cs[j] += v; cq[j] += v * v; }
                slice[(quad * 4 + r) * 64 + ((j ^ quad) * 16) + lrow] = f2bf(v);
            }
        }
        __syncthreads();
        // readback: 128 uint4 chunks (16 rows x 8 chunks), lane handles 2
#pragma unroll
        for (int c = 0; c < 2; ++c) {
            int ch = lane + c * 64;
            int lr = ch >> 3, sg = ch & 7;
            int grow = tile_m + rw + i * 16 + lr;
            if (grow < M) {
                const bf16* srcp = slice + lr * 64 + (((sg >> 1) ^ (lr >> 2)) << 4) + ((sg & 1) << 3);
                uint4 v = *(const uint4*)srcp;
                *(uint4*)(C + (size_t)grow * HID + tile_n + cw + sg * 8) = v;
            }
        }
        __syncthreads();
    }

    // reduce across the 4 quads that share each (j,lrow) column
#pragma unroll
    for (int j = 0; j < 4; ++j) {
        cs[j] += __shfl_xor(cs[j], 16, 64); cs[j] += __shfl_xor(cs[j], 32, 64);
        cq[j] += __shfl_xor(cq[j], 16, 64); cq[j] += __shfl_xor(cq[j], 32, 64);
    }
    if (quad == 0) {
#pragma unroll
        for (int j = 0; j < 4; ++j) {
            sred[wave][j * 16 + lrow] = cs[j];
            qred[wave][j * 16 + lrow] = cq[j];
        }
    }
    __syncthreads();
    int bid = blockIdx.y * gridDim.x + blockIdx.x;
    if (tid < 128) {
        int grp = tid >> 6, idx = tid & 63;
        psum[(size_t)bid * 128 + tid] = sred[grp][idx] + sred[grp + 2][idx];
    } else {
        int t = tid - 128;
        int grp = t >> 6, idx = t & 63;
        psq[(size_t)bid * 128 + t] = qred[grp][idx] + qred[grp + 2][idx];
    }
}

// reduce per-block partials -> stats[0..255]=sum, stats[256..511]=sumsq
__global__ void bn_finalize_kernel(const float* __restrict__ psum, const float* __restrict__ psq,
                                   float* __restrict__ stats, int nby) {
    const float* src = blockIdx.y ? psq : psum;
    int c = threadIdx.x;           // 0..255 = global column
    int bx = c >> 7, cl = c & 127;
    int per = (nby + gridDim.x - 1) / gridDim.x;
    int b0 = blockIdx.x * per, b1 = min(b0 + per, nby);
    float s = 0.f;
    for (int by = b0; by < b1; ++by) s += src[(size_t)(by * 2 + bx) * 128 + cl];
    atomicAdd(&stats[blockIdx.y * HID + c], s);
}

// ---------------- BN apply + ReLU (layer 1; also emits fp8 copy for gather) ----------------

__global__ void bn_apply_relu_kernel(bf16* __restrict__ h, unsigned char* __restrict__ hf8,
                                     const float* __restrict__ stats,
                                     const float* __restrict__ g, const float* __restrict__ be,
                                     int M) {
    int i4 = blockIdx.x * blockDim.x + threadIdx.x;
    int total4 = M * (HID / 4);
    if (i4 >= total4) return;
    int col4 = i4 & (HID / 4 - 1);
    ushort4 v = ((const ushort4*)h)[i4];
    float invN = 1.0f / (float)M;
    float o[4] = {bf2f(v.x), bf2f(v.y), bf2f(v.z), bf2f(v.w)};
#pragma unroll
    for (int j = 0; j < 4; ++j) {
        int col = col4 * 4 + j;
        float mu = stats[col] * invN;
        float var = stats[HID + col] * invN - mu * mu;
        float sc = rsqrtf(var + BN_EPS) * g[col];
        float val = (o[j] - mu) * sc + be[col];
        o[j] = val > 0.f ? val : 0.f;
    }
    ushort4 r;
    r.x = f2bf(o[0]); r.y = f2bf(o[1]); r.z = f2bf(o[2]); r.w = f2bf(o[3]);
    ((ushort4*)h)[i4] = r;
    ((unsigned int*)hf8)[i4] = pack4_fp8(o[0], o[1], o[2], o[3]);
}

// ---------------- final FC (MFMA) with fused BN2+ReLU ----------------

#define BSTR 264   // 256 + 8 pad

__global__ __launch_bounds__(256) void fc_bn_mfma_kernel(
    const bf16* __restrict__ h, const float* __restrict__ stats,
    const float* __restrict__ g, const float* __restrict__ be,
    const bf16* __restrict__ WfcT, const float* __restrict__ bfc,
    float* __restrict__ out, int M) {
    __shared__ bf16 Bs[32 * BSTR];
    __shared__ float sc_s[HID], sh_s[HID];
    int tid = threadIdx.x;
    for (int i = tid; i < 32 * 32; i += 256) {   // 1024 16B chunks
        int rrow = i >> 5, seg = i & 31;
        *(uint4*)(Bs + rrow * BSTR + seg * 8) = *(const uint4*)(WfcT + (size_t)rrow * HID + seg * 8);
    }
    {
        float invN = 1.0f / (float)M;
        float mu = stats[tid] * invN;
        float var = stats[HID + tid] * invN - mu * mu;
        float s = rsqrtf(var + BN_EPS) * g[tid];
        sc_s[tid] = s;
        sh_s[tid] = be[tid] - mu * s;
    }
    __syncthreads();
    int wave = tid >> 6, lane = tid & 63, lrow = lane & 15, quad = lane >> 4;
    int row = blockIdx.x * 64 + wave * 16 + lrow;
    const bf16* hrow = h + (size_t)row * HID;
    float4v acc0 = {0.f, 0.f, 0.f, 0.f}, acc1 = {0.f, 0.f, 0.f, 0.f};
#pragma unroll
    for (int ks = 0; ks < 8; ++ks) {
        int k0 = ks * 32 + quad * 8;
        uint4 av = {0u, 0u, 0u, 0u};
        if (row < M) av = *(const uint4*)(hrow + k0);
        union { unsigned int u[4]; short8 s8; } cvt;
        unsigned int* avp = (unsigned int*)&av;
#pragma unroll
        for (int t = 0; t < 4; ++t) {
            int k = k0 + t * 2;
            float v0 = blo(avp[t]) * sc_s[k] + sh_s[k];
            float v1 = bhi(avp[t]) * sc_s[k + 1] + sh_s[k + 1];
            v0 = v0 > 0.f ? v0 : 0.f;
            v1 = v1 > 0.f ? v1 : 0.f;
            cvt.u[t] = pack2(v0, v1);
        }
        short8 b0 = *(const short8*)(Bs + lrow * BSTR + k0);
        short8 b1 = *(const short8*)(Bs + (16 + lrow) * BSTR + k0);
        acc0 = __builtin_amdgcn_mfma_f32_16x16x32_bf16(cvt.s8, b0, acc0, 0, 0, 0);
        acc1 = __builtin_amdgcn_mfma_f32_16x16x32_bf16(cvt.s8, b1, acc1, 0, 0, 0);
    }
    int orow = blockIdx.x * 64 + wave * 16 + quad * 4;
    float bv0 = bfc[lrow], bv1 = bfc[16 + lrow];
#pragma unroll
    for (int r = 0; r < 4; ++r) {
        int rr = orow + r;
        if (rr < M) {
            out[(size_t)rr * N_CLS + lrow] = acc0[r] + bv0;
            out[(size_t)rr * N_CLS + 16 + lrow] = acc1[r] + bv1;
        }
    }
}

// ---------------- launch ----------------

extern "C" void kernel_launch(void* const* d_in, const int* in_sizes, int n_in,
                              void* d_out, int out_size, void* d_ws, size_t ws_size,
                              hipStream_t stream) {
    const float* x   = (const float*)d_in[0];
    const int* esrc  = (const int*)d_in[1];
    const int* edst  = (const int*)d_in[2];
    const float* W1l = (const float*)d_in[3];
    const float* b1  = (const float*)d_in[4];
    const float* W1r = (const float*)d_in[5];
    const float* g1  = (const float*)d_in[6];
    const float* be1 = (const float*)d_in[7];
    const float* W2l = (const float*)d_in[8];
    const float* b2  = (const float*)d_in[9];
    const float* W2r = (const float*)d_in[10];
    const float* g2  = (const float*)d_in[11];
    const float* be2 = (const float*)d_in[12];
    const float* Wfc = (const float*)d_in[13];
    const float* bfc = (const float*)d_in[14];
    float* out = (float*)d_out;

    char* ws = (char*)d_ws;
    size_t o = 0;
    auto carve = [&](size_t bytes) {
        char* p = ws + o;
        o = (o + bytes + 255) & ~(size_t)255;
        return p;
    };
    int*   off    = (int*)carve((N_NODES + 1) * sizeof(int));
    int*   cursor = (int*)carve(N_NODES * sizeof(int));
    int*   csr    = (int*)carve(N_EDGES * sizeof(int));
    int*   bsums  = (int*)carve(SCAN_NB * sizeof(int));
    int*   boffs  = (int*)carve(SCAN_NB * sizeof(int));
    int*   bcur   = (int*)carve(NBUCK * sizeof(int));
    float* stats1 = (float*)carve(2 * HID * sizeof(float));
    float* stats2 = (float*)carve(2 * HID * sizeof(float));
    float* psum   = (float*)carve((size_t)GEMM_NB * 128 * sizeof(float));
    float* psq    = (float*)carve((size_t)GEMM_NB * 128 * sizeof(float));
    bf16*  w1lt   = (bf16*)carve((size_t)IN_DIM * HID * sizeof(bf16));
    bf16*  w1rt   = (bf16*)carve((size_t)IN_DIM * HID * sizeof(bf16));
    bf16*  w2lt   = (bf16*)carve((size_t)HID * HID * sizeof(bf16));
    bf16*  w2rt   = (bf16*)carve((size_t)HID * HID * sizeof(bf16));
    bf16*  wfct   = (bf16*)carve((size_t)N_CLS * HID * sizeof(bf16));
    bf16*  agg    = (bf16*)carve((size_t)N_NODES * HID * sizeof(bf16));
    bf16*  h1     = (bf16*)carve((size_t)N_NODES * HID * sizeof(bf16));
    bf16*  h2     = (bf16*)carve((size_t)N_NODES * HID * sizeof(bf16));
    // overlays inside the h2 region (lifetimes stream-ordered disjoint):
    //   xb  = h2[0   : 25.6MB]  bf16 x   — dead after gemm1
    //   xf8 = h2[25.6: 38.4MB]  fp8 x    — dead after aggregate1
    //   h1f8= h2[0   : 25.6MB]  fp8 bn(h1) — written post-gemm1, read by aggregate2,
    //                                        then gemm2 overwrites h2
    bf16*          xb   = h2;
    unsigned char* xf8  = (unsigned char*)h2 + (size_t)N_NODES * IN_DIM * sizeof(bf16);
    unsigned char* h1f8 = (unsigned char*)h2;
    // overlay inside the agg region (dead until aggregate1 writes it):
    //   bstore = 16 buckets x 112K edges x 8B = 14.3 MB < 51.2 MB
    int2*          bstore = (int2*)agg;
    // overlay inside the h1 region (dead until gemm1 writes it):
    //   partial = HSUBS x N_NODES ints = 12.8 MB < 51.2 MB
    int*           partial = (int*)h1;

    if (o > ws_size) return;  // clean fail instead of fault

    hipMemsetAsync(bcur, 0, NBUCK * sizeof(int), stream);
    hipMemsetAsync(stats1, 0, 2 * HID * sizeof(float), stream);
    hipMemsetAsync(stats2, 0, 2 * HID * sizeof(float), stream);

    // CSR build: bucket scatter -> LDS-privatized degree hist -> scans (scan1 also
    // produces the per-slice exclusive prefix) -> deterministic per-bucket fill.
    // Zero per-edge global atomics anywhere.
    bucket_scatter_kernel<<<PASSA_NB, 256, 0, stream>>>(esrc, edst, bcur, bstore);
    bucket_hist_kernel<<<NBUCK * HSUBS, 256, 0, stream>>>(bstore, bcur, partial);
    scan1_kernel<<<SCAN_NB, 256, 0, stream>>>(partial, cursor, bsums);   // cursor <- counts
    scan2_kernel<<<1, 128, 0, stream>>>(bsums, boffs);
    scan3_kernel<<<SCAN_NB, 256, 0, stream>>>(cursor, boffs, off);
    fill_bucket_kernel<<<NBUCK * HSUBS, 256, 0, stream>>>(bstore, bcur, off, partial, csr);

    // prep: x -> bf16 + fp8, all weights -> bf16 transposed
    convert_x_kernel<<<(N_NODES * IN_DIM / 4 + 255) / 256, 256, 0, stream>>>(x, xb, xf8);
    {
        int total = 2 * IN_DIM * HID + 2 * HID * HID + HID * N_CLS;
        prep_weights_kernel<<<(total + 255) / 256, 256, 0, stream>>>(
            W1l, W1r, W2l, W2r, Wfc, w1lt, w1rt, w2lt, w2rt, wfct);
    }

    const dim3 ggrid(HID / 128, GEMM_NBY);

    // ---- layer 1 ----
    aggregate1_kernel<<<(N_NODES * 16 + 255) / 256, 256, 0, stream>>>(xf8, off, csr, agg);
    gemm_dual_mfma<<<ggrid, 256, 0, stream>>>(
        agg, w1lt, IN_DIM, xb, w1rt, IN_DIM, b1, h1, N_NODES, psum, psq);
    bn_finalize_kernel<<<dim3(8, 2), 256, 0, stream>>>(psum, psq, stats1, GEMM_NBY);
    {
        int total4 = N_NODES * (HID / 4);
        bn_apply_relu_kernel<<<(total4 + 255) / 256, 256, 0, stream>>>(h1, h1f8, stats1, g1, be1, N_NODES);
    }

    // ---- layer 2 ----
    aggregate2_kernel<<<(N_NODES * 32 + 255) / 256, 256, 0, stream>>>(h1f8, off, csr, agg);
    gemm_dual_mfma<<<ggrid, 256, 0, stream>>>(
        agg, w2lt, HID, h1, w2rt, HID, b2, h2, N_NODES, psum, psq);
    bn_finalize_kernel<<<dim3(8, 2), 256, 0, stream>>>(psum, psq, stats2, GEMM_NBY);

    // ---- final FC (MFMA) with fused BN2+ReLU ----
    fc_bn_mfma_kernel<<<(N_NODES + 63) / 64, 256, 0, stream>>>(
        h2, stats2, g2, be2, wfct, bfc, out, N_NODES);
}

// Round 5
// 454.112 us; speedup vs baseline: 1.2693x; 1.0202x over previous
//
#include <hip/hip_runtime.h>

#define N_NODES 100000
#define N_EDGES 1600000
#define IN_DIM 128
#define HID 256
#define N_CLS 32
#define BN_EPS 1e-5f

#define SCAN_CHUNK 1024
#define SCAN_NB ((N_NODES + SCAN_CHUNK - 1) / SCAN_CHUNK)   // 98
#define GEMM_NBY ((N_NODES + 127) / 128)                    // 782
#define GEMM_NB (GEMM_NBY * 2)                              // 1564 blocks (2 n-tiles)

// ---- bucketed CSR fill parameters ----
#define NBUCK 16
#define BUCK_NODES 6250        // 16 * 6250 = 100000 exactly
#define BUCK_CAP 112000        // expected 100K/bucket, sd ~306 -> huge margin
#define PASSA_CHUNK 2048       // edges staged per block (16 KB LDS)
#define PASSA_NB ((N_EDGES + PASSA_CHUNK - 1) / PASSA_CHUNK)  // 782
#define HSUBS 32               // histogram/fill slices per bucket

typedef unsigned short bf16;
typedef __attribute__((ext_vector_type(8))) short short8;
typedef __attribute__((ext_vector_type(4))) float float4v;
typedef __attribute__((ext_vector_type(2))) float floatx2;

__device__ __forceinline__ float bf2f(bf16 h) {
    return __uint_as_float(((unsigned int)h) << 16);
}
__device__ __forceinline__ bf16 f2bf(float f) {
    unsigned int u = __float_as_uint(f);
    u += 0x7FFFu + ((u >> 16) & 1u);   // round-to-nearest-even
    return (bf16)(u >> 16);
}
__device__ __forceinline__ float blo(unsigned int u) { return __uint_as_float(u << 16); }
__device__ __forceinline__ float bhi(unsigned int u) { return __uint_as_float(u & 0xFFFF0000u); }
__device__ __forceinline__ unsigned int pack2(float lo, float hi) {
    return (unsigned int)f2bf(lo) | ((unsigned int)f2bf(hi) << 16);
}

// fp8 (OCP e4m3 on gfx950) hardware conversions
__device__ __forceinline__ void acc16_fp8(uint4 w, floatx2* a) {
    a[0] += __builtin_amdgcn_cvt_pk_f32_fp8(w.x, false);
    a[1] += __builtin_amdgcn_cvt_pk_f32_fp8(w.x, true);
    a[2] += __builtin_amdgcn_cvt_pk_f32_fp8(w.y, false);
    a[3] += __builtin_amdgcn_cvt_pk_f32_fp8(w.y, true);
    a[4] += __builtin_amdgcn_cvt_pk_f32_fp8(w.z, false);
    a[5] += __builtin_amdgcn_cvt_pk_f32_fp8(w.z, true);
    a[6] += __builtin_amdgcn_cvt_pk_f32_fp8(w.w, false);
    a[7] += __builtin_amdgcn_cvt_pk_f32_fp8(w.w, true);
}
__device__ __forceinline__ unsigned int pack4_fp8(float a, float b, float c, float d) {
    int p = 0;
    p = __builtin_amdgcn_cvt_pk_fp8_f32(a, b, p, false);
    p = __builtin_amdgcn_cvt_pk_fp8_f32(c, d, p, true);
    return (unsigned int)p;
}

// async global->LDS, 16B per lane, wave-uniform LDS base + lane*16
__device__ __forceinline__ void gload16(const void* g, void* l) {
    __builtin_amdgcn_global_load_lds(
        (const __attribute__((address_space(1))) void*)g,
        (__attribute__((address_space(3))) void*)l, 16, 0, 0);
}

// ---------------- CSR build: pass A — bucket scatter (no global atomics) ----------------

__global__ __launch_bounds__(256) void bucket_scatter_kernel(
    const int* __restrict__ esrc, const int* __restrict__ edst,
    int* __restrict__ bcur, int2* __restrict__ bstore) {
    __shared__ int lhist[NBUCK], lbase[NBUCK], gbase[NBUCK], lcur[NBUCK];
    __shared__ int2 stage[PASSA_CHUNK];    // 16 KB
    const int tid = threadIdx.x;
    if (tid < NBUCK) lhist[tid] = 0;
    __syncthreads();

    const int base = blockIdx.x * PASSA_CHUNK;
    const int nedge = min(PASSA_CHUNK, N_EDGES - base);
    // N_EDGES % 8 == 0, so each thread's 8-edge chunk is all-or-nothing.
    const bool act = (tid * 8) < nedge;
    int s[8], d[8], bk[8];
    if (act) {
        const int4* s4 = (const int4*)(esrc + base + tid * 8);
        const int4* d4 = (const int4*)(edst + base + tid * 8);
#pragma unroll
        for (int t = 0; t < 2; ++t) {
            int4 sv = s4[t], dv = d4[t];
            s[t * 4 + 0] = sv.x; s[t * 4 + 1] = sv.y; s[t * 4 + 2] = sv.z; s[t * 4 + 3] = sv.w;
            d[t * 4 + 0] = dv.x; d[t * 4 + 1] = dv.y; d[t * 4 + 2] = dv.z; d[t * 4 + 3] = dv.w;
        }
#pragma unroll
        for (int u = 0; u < 8; ++u) {
            bk[u] = (int)((unsigned)d[u] / BUCK_NODES);
            atomicAdd(&lhist[bk[u]], 1);        // block-local bucket counts (LDS only)
        }
    }
    __syncthreads();
    if (tid == 0) {
        int run = 0;
#pragma unroll
        for (int b = 0; b < NBUCK; ++b) { lbase[b] = run; lcur[b] = run; run += lhist[b]; }
    }
    if (tid < NBUCK) gbase[tid] = atomicAdd(&bcur[tid], lhist[tid]);
    __syncthreads();
    if (act) {
#pragma unroll
        for (int u = 0; u < 8; ++u) {
            int p = atomicAdd(&lcur[bk[u]], 1);
            stage[p] = make_int2(s[u], d[u]);
        }
    }
    __syncthreads();
    // write out: LDS position p -> global bstore[b*CAP + gbase[b] + (p - lbase[b])]
    for (int p = tid; p < nedge; p += 256) {
        int2 e = stage[p];
        int b = (int)((unsigned)e.y / BUCK_NODES);
        int gp = gbase[b] + (p - lbase[b]);
        if (gp < BUCK_CAP) bstore[(size_t)b * BUCK_CAP + gp] = e;
    }
}

// ---------------- CSR build: per-(bucket,slice) degree histogram (LDS-privatized) ----------------

__global__ __launch_bounds__(256) void bucket_hist_kernel(
    const int2* __restrict__ bstore, const int* __restrict__ bcnt,
    int* __restrict__ partial) {
    __shared__ int hist[BUCK_NODES];   // 25000 B
    const int bk = blockIdx.x & (NBUCK - 1);
    const int sl = blockIdx.x >> 4;
    for (int i = threadIdx.x; i < BUCK_NODES; i += 256) hist[i] = 0;
    __syncthreads();
    const int n = bcnt[bk];
    const int per = (n + HSUBS - 1) / HSUBS;
    const int i0 = sl * per, i1 = min(i0 + per, n);
    const int2* ep = bstore + (size_t)bk * BUCK_CAP;
    const int nbase = bk * BUCK_NODES;
    for (int i = i0 + threadIdx.x; i < i1; i += 256) {
        atomicAdd(&hist[ep[i].y - nbase], 1);
    }
    __syncthreads();
    int* dst = partial + (size_t)sl * N_NODES + nbase;
    for (int i = threadIdx.x; i < BUCK_NODES; i += 256) dst[i] = hist[i];
}

// ---------------- CSR build: pass B — per-bucket deterministic fill (LDS atomics only) ----------------

__global__ __launch_bounds__(256) void fill_bucket_kernel(
    const int2* __restrict__ bstore, const int* __restrict__ bcnt,
    const int* __restrict__ off, const int* __restrict__ partial,
    int* __restrict__ csr) {
    __shared__ int basec[BUCK_NODES];   // 25000 B
    const int bk = blockIdx.x & (NBUCK - 1);
    const int sl = blockIdx.x >> 4;
    const int nbase = bk * BUCK_NODES;
    const int* prow = partial + (size_t)sl * N_NODES + nbase;
    const int* orow = off + nbase;
    for (int i = threadIdx.x; i < BUCK_NODES; i += 256) basec[i] = orow[i] + prow[i];
    __syncthreads();
    const int n = bcnt[bk];
    const int per = (n + HSUBS - 1) / HSUBS;
    const int i0 = sl * per, i1 = min(i0 + per, n);
    const int2* ep = bstore + (size_t)bk * BUCK_CAP;
    for (int i = i0 + threadIdx.x; i < i1; i += 256) {
        int2 e = ep[i];
        int p = atomicAdd(&basec[e.y - nbase], 1);
        csr[p] = e.x;
    }
}

// ---------------- prefix scans ----------------
// scan1 folds the HSUBS partial histograms into counts AND rewrites partial in place
// as the exclusive prefix across slices (per node), for the deterministic fill.

__global__ void scan1_kernel(int* __restrict__ partial, int* __restrict__ counts,
                             int* __restrict__ bsums) {
    __shared__ int wsum[4];
    int base = blockIdx.x * SCAN_CHUNK + threadIdx.x * 4;
    int c0 = 0, c1 = 0, c2 = 0, c3 = 0;
    if (base + 4 <= N_NODES) {
#pragma unroll
        for (int sl = 0; sl < HSUBS; ++sl) {
            int* p = partial + (size_t)sl * N_NODES + base;
            int4 v = *(const int4*)p;
            int4 w; w.x = c0; w.y = c1; w.z = c2; w.w = c3;
            *(int4*)p = w;                     // exclusive prefix (before adding v)
            c0 += v.x; c1 += v.y; c2 += v.z; c3 += v.w;
        }
        int4 w; w.x = c0; w.y = c1; w.z = c2; w.w = c3;
        *(int4*)(counts + base) = w;
    } else {
        for (int j = 0; j < 4; ++j) {
            if (base + j < N_NODES) {
                int c = 0;
                for (int sl = 0; sl < HSUBS; ++sl) {
                    int* p = partial + (size_t)sl * N_NODES + base + j;
                    int v = *p; *p = c; c += v;
                }
                counts[base + j] = c;
                if (j == 0) c0 = c; else if (j == 1) c1 = c; else if (j == 2) c2 = c; else c3 = c;
            }
        }
    }
    int s = c0 + c1 + c2 + c3;
    for (int d = 32; d > 0; d >>= 1) s += __shfl_down(s, d, 64);
    if ((threadIdx.x & 63) == 0) wsum[threadIdx.x >> 6] = s;
    __syncthreads();
    if (threadIdx.x == 0) bsums[blockIdx.x] = wsum[0] + wsum[1] + wsum[2] + wsum[3];
}

__global__ void scan2_kernel(const int* __restrict__ bsums, int* __restrict__ boffs) {
    __shared__ int sh[128];
    int i = threadIdx.x;
    int v = (i < SCAN_NB) ? bsums[i] : 0;
    sh[i] = v;
    __syncthreads();
    for (int d = 1; d < 128; d <<= 1) {
        int t = (i >= d) ? sh[i - d] : 0;
        __syncthreads();
        sh[i] += t;
        __syncthreads();
    }
    if (i < SCAN_NB) boffs[i] = sh[i] - v;
}

__global__ void scan3_kernel(const int* __restrict__ counts, const int* __restrict__ boffs,
                             int* __restrict__ off) {
    __shared__ int sh[256];
    int tid = threadIdx.x;
    int base = blockIdx.x * SCAN_CHUNK + tid * 4;
    int c0 = 0, c1 = 0, c2 = 0, c3 = 0;
    if (base + 4 <= N_NODES) {
        int4 v = *(const int4*)(counts + base);
        c0 = v.x; c1 = v.y; c2 = v.z; c3 = v.w;
    } else {
        if (base + 0 < N_NODES) c0 = counts[base + 0];
        if (base + 1 < N_NODES) c1 = counts[base + 1];
        if (base + 2 < N_NODES) c2 = counts[base + 2];
        if (base + 3 < N_NODES) c3 = counts[base + 3];
    }
    int ts = c0 + c1 + c2 + c3;
    sh[tid] = ts;
    __syncthreads();
    for (int d = 1; d < 256; d <<= 1) {
        int t = (tid >= d) ? sh[tid - d] : 0;
        __syncthreads();
        sh[tid] += t;
        __syncthreads();
    }
    int run = boffs[blockIdx.x] + sh[tid] - ts;
    if (base + 0 < N_NODES) off[base + 0] = run; run += c0;
    if (base + 1 < N_NODES) off[base + 1] = run; run += c1;
    if (base + 2 < N_NODES) off[base + 2] = run; run += c2;
    if (base + 3 < N_NODES) off[base + 3] = run;
    if (blockIdx.x == 0 && tid == 0) off[N_NODES] = N_EDGES;
}

// ---------------- x fp32 -> bf16 + fp8 ----------------

__global__ void convert_x_kernel(const float* __restrict__ x, bf16* __restrict__ xb,
                                 unsigned char* __restrict__ xf8) {
    int i = blockIdx.x * blockDim.x + threadIdx.x;
    int total4 = N_NODES * IN_DIM / 4;
    if (i >= total4) return;
    float4 v = ((const float4*)x)[i];
    ushort4 r;
    r.x = f2bf(v.x); r.y = f2bf(v.y); r.z = f2bf(v.z); r.w = f2bf(v.w);
    ((ushort4*)xb)[i] = r;
    ((unsigned int*)xf8)[i] = pack4_fp8(v.x, v.y, v.z, v.w);
}

// ---------------- combined weight prep ----------------

__global__ void prep_weights_kernel(const float* __restrict__ W1l, const float* __restrict__ W1r,
                                    const float* __restrict__ W2l, const float* __restrict__ W2r,
                                    const float* __restrict__ Wfc,
                                    bf16* __restrict__ w1lt, bf16* __restrict__ w1rt,
                                    bf16* __restrict__ w2lt, bf16* __restrict__ w2rt,
                                    bf16* __restrict__ wfct) {
    const int S1 = IN_DIM * HID;   // 32768
    const int S2 = HID * HID;      // 65536
    const int S3 = HID * N_CLS;    // 8192
    int i = blockIdx.x * blockDim.x + threadIdx.x;
    if (i < 2 * S1 + 2 * S2) {
        const float* W; bf16* Wt; int K, idx;
        if (i < S1)          { W = W1l; Wt = w1lt; K = IN_DIM; idx = i; }
        else if (i < 2 * S1) { W = W1r; Wt = w1rt; K = IN_DIM; idx = i - S1; }
        else if (i < 2 * S1 + S2) { W = W2l; Wt = w2lt; K = HID; idx = i - 2 * S1; }
        else                 { W = W2r; Wt = w2rt; K = HID; idx = i - 2 * S1 - S2; }
        int k = idx / HID, n = idx - k * HID;
        Wt[(size_t)n * K + k] = f2bf(W[idx]);
    } else if (i < 2 * S1 + 2 * S2 + S3) {
        int idx = i - 2 * S1 - 2 * S2;       // idx = k*32 + n
        int k = idx >> 5, n = idx & 31;
        wfct[(size_t)n * HID + k] = f2bf(Wfc[idx]);
    }
}

// ---------------- mean aggregation (fp8 uint4 gathers, 32-bit addressing) ----------------
// aggregate1: row = 128 B = 8 uint4, 8 lanes/node, 16 B/lane.
// aggregate2: row = 256 B = 16 uint4, 16 lanes/node, 16 B/lane.
// 8/4/1 unroll keeps up to 128 B per lane in flight; packed floatx2 accumulation.

__global__ __launch_bounds__(256) void aggregate1_kernel(
    const unsigned char* __restrict__ xf8, const int* __restrict__ off,
    const int* __restrict__ csr, bf16* __restrict__ out) {
    int t = blockIdx.x * blockDim.x + threadIdx.x;
    int node = t >> 3;
    int sl = t & 7;
    if (node >= N_NODES) return;
    int s = off[node], e = off[node + 1];
    float inv = 1.0f / (float)max(e - s, 1);
    const uint4* f = (const uint4*)xf8;   // row = 8 uint4
    floatx2 a[8];
#pragma unroll
    for (int k = 0; k < 8; ++k) a[k] = (floatx2){0.f, 0.f};
    int i = s;
    for (; i + 8 <= e; i += 8) {
        uint4 w[8];
#pragma unroll
        for (int u = 0; u < 8; ++u) w[u] = f[csr[i + u] * 8 + sl];
#pragma unroll
        for (int u = 0; u < 8; ++u) acc16_fp8(w[u], a);
    }
    for (; i + 4 <= e; i += 4) {
        uint4 w[4];
#pragma unroll
        for (int u = 0; u < 4; ++u) w[u] = f[csr[i + u] * 8 + sl];
#pragma unroll
        for (int u = 0; u < 4; ++u) acc16_fp8(w[u], a);
    }
    for (; i < e; ++i) acc16_fp8(f[csr[i] * 8 + sl], a);
    uint4 r0, r1;
    r0.x = pack2(a[0].x * inv, a[0].y * inv);
    r0.y = pack2(a[1].x * inv, a[1].y * inv);
    r0.z = pack2(a[2].x * inv, a[2].y * inv);
    r0.w = pack2(a[3].x * inv, a[3].y * inv);
    r1.x = pack2(a[4].x * inv, a[4].y * inv);
    r1.y = pack2(a[5].x * inv, a[5].y * inv);
    r1.z = pack2(a[6].x * inv, a[6].y * inv);
    r1.w = pack2(a[7].x * inv, a[7].y * inv);
    ((uint4*)out)[node * 16 + sl * 2] = r0;
    ((uint4*)out)[node * 16 + sl * 2 + 1] = r1;
}

__global__ __launch_bounds__(256) void aggregate2_kernel(
    const unsigned char* __restrict__ hf8, const int* __restrict__ off,
    const int* __restrict__ csr, bf16* __restrict__ out) {
    int t = blockIdx.x * blockDim.x + threadIdx.x;
    int node = t >> 4;
    int sl = t & 15;
    if (node >= N_NODES) return;
    int s = off[node], e = off[node + 1];
    float inv = 1.0f / (float)max(e - s, 1);
    const uint4* f = (const uint4*)hf8;   // row = 16 uint4
    floatx2 a[8];
#pragma unroll
    for (int k = 0; k < 8; ++k) a[k] = (floatx2){0.f, 0.f};
    int i = s;
    for (; i + 8 <= e; i += 8) {
        uint4 w[8];
#pragma unroll
        for (int u = 0; u < 8; ++u) w[u] = f[csr[i + u] * 16 + sl];
#pragma unroll
        for (int u = 0; u < 8; ++u) acc16_fp8(w[u], a);
    }
    for (; i + 4 <= e; i += 4) {
        uint4 w[4];
#pragma unroll
        for (int u = 0; u < 4; ++u) w[u] = f[csr[i + u] * 16 + sl];
#pragma unroll
        for (int u = 0; u < 4; ++u) acc16_fp8(w[u], a);
    }
    for (; i < e; ++i) acc16_fp8(f[csr[i] * 16 + sl], a);
    uint4 r0, r1;
    r0.x = pack2(a[0].x * inv, a[0].y * inv);
    r0.y = pack2(a[1].x * inv, a[1].y * inv);
    r0.z = pack2(a[2].x * inv, a[2].y * inv);
    r0.w = pack2(a[3].x * inv, a[3].y * inv);
    r1.x = pack2(a[4].x * inv, a[4].y * inv);
    r1.y = pack2(a[5].x * inv, a[5].y * inv);
    r1.z = pack2(a[6].x * inv, a[6].y * inv);
    r1.w = pack2(a[7].x * inv, a[7].y * inv);
    ((uint4*)out)[node * 32 + sl * 2] = r0;
    ((uint4*)out)[node * 32 + sl * 2 + 1] = r1;
}

// ---------------- MFMA dual GEMM: global_load_lds + 3-buffer 2-deep prefetch ----------------

#define AT_SZ 4096   // bf16 per tile buffer (128 rows x 32)

__device__ __forceinline__ void stage_tile(
    const bf16* __restrict__ Ap, const bf16* __restrict__ Wp, int K, int k0,
    int tile_m, int tile_n, int M, int wave, int lane,
    bf16* bufA, bf16* bufW) {
    // tile = 8 KB; wave w covers bytes [w*2048,(w+1)*2048) via 2 x 1KB gload_lds
#pragma unroll
    for (int is = 0; is < 2; ++is) {
        int lin = (wave * 2 + is) * 1024 + lane * 16;   // byte offset in tile
        int row = lin >> 6;                              // 64B per row
        int seg = (lin >> 4) & 3;
        int ga = min(tile_m + row, M - 1);               // clamp OOB rows (results discarded)
        gload16(Ap + (size_t)ga * K + k0 + seg * 8, (char*)bufA + (wave * 2 + is) * 1024);
        gload16(Wp + (size_t)(tile_n + row) * K + k0 + seg * 8, (char*)bufW + (wave * 2 + is) * 1024);
    }
}

__global__ __launch_bounds__(256) void gemm_dual_mfma(
    const bf16* __restrict__ A, const bf16* __restrict__ WtA, int KA,
    const bf16* __restrict__ Bm, const bf16* __restrict__ WtB, int KB,
    const float* __restrict__ bias, bf16* __restrict__ C, int M,
    float* __restrict__ psum, float* __restrict__ psq) {
    __shared__ bf16 As[3 * AT_SZ];
    __shared__ bf16 Ws[3 * AT_SZ];
    __shared__ float sred[4][64];
    __shared__ float qred[4][64];
    const int tid = threadIdx.x;
    const int lane = tid & 63;
    const int wave = tid >> 6;
    const int rw = (wave >> 1) * 64;
    const int cw = (wave & 1) * 64;
    const int lrow = lane & 15;
    const int quad = lane >> 4;
    const int tile_m = blockIdx.y * 128;
    const int tile_n = blockIdx.x * 128;

    float4v acc[4][4];
#pragma unroll
    for (int i = 0; i < 4; ++i)
#pragma unroll
        for (int j = 0; j < 4; ++j) acc[i][j] = (float4v){0.f, 0.f, 0.f, 0.f};

    const int NTA = KA >> 5;
    const int NT = NTA + (KB >> 5);
    // tile source resolver (uniform across block)
    auto tsrc = [&](int t, const bf16*& Ap, const bf16*& Wp, int& K, int& k0) {
        if (t < NTA) { Ap = A;  Wp = WtA; K = KA; k0 = t << 5; }
        else         { Ap = Bm; Wp = WtB; K = KB; k0 = (t - NTA) << 5; }
    };

    // prologue: stage tiles 0 and 1 (NT >= 4 always)
#pragma unroll
    for (int t = 0; t < 2; ++t) {
        const bf16 *Ap, *Wp; int K, k0; tsrc(t, Ap, Wp, K, k0);
        stage_tile(Ap, Wp, K, k0, tile_m, tile_n, M, wave, lane,
                   As + t * AT_SZ, Ws + t * AT_SZ);
    }

    for (int t = 0; t < NT; ++t) {
        if (t + 2 < NT) {
            const bf16 *Ap, *Wp; int K, k0; tsrc(t + 2, Ap, Wp, K, k0);
            int b = (t + 2) % 3;
            stage_tile(Ap, Wp, K, k0, tile_m, tile_n, M, wave, lane,
                       As + b * AT_SZ, Ws + b * AT_SZ);
        }
        // per-wave: 4 vmem issues per stage; keep up to 2 future tiles (8) in flight
        if (t + 2 < NT)      asm volatile("s_waitcnt vmcnt(8)" ::: "memory");
        else if (t + 1 < NT) asm volatile("s_waitcnt vmcnt(4)" ::: "memory");
        else                 asm volatile("s_waitcnt vmcnt(0)" ::: "memory");
        __builtin_amdgcn_s_barrier();
        asm volatile("" ::: "memory");

        const bf16* bA = As + (t % 3) * AT_SZ;
        const bf16* bW = Ws + (t % 3) * AT_SZ;
        short8 a[4], b[4];
#pragma unroll
        for (int i = 0; i < 4; ++i)
            a[i] = *(const short8*)(bA + (rw + i * 16 + lrow) * 32 + quad * 8);
#pragma unroll
        for (int j = 0; j < 4; ++j)
            b[j] = *(const short8*)(bW + (cw + j * 16 + lrow) * 32 + quad * 8);
#pragma unroll
        for (int i = 0; i < 4; ++i)
#pragma unroll
            for (int j = 0; j < 4; ++j)
                acc[i][j] = __builtin_amdgcn_mfma_f32_16x16x32_bf16(a[i], b[j], acc[i][j], 0, 0, 0);

        asm volatile("" ::: "memory");
        __builtin_amdgcn_s_barrier();   // protect buf (t%3) from stage at t+1 (writes (t+3)%3)
    }

    // ---- epilogue: C/D layout col=lane&15, row=quad*4+reg [verified m89] ----
    // Per-wave LDS slice (16x64 bf16 = 2 KB) -> coalesced 16B global stores.
    // j-block slot XOR'd with writer quad (= row>>2) -> conflict-free scalar writes.
    bf16* slice = As + wave * 1024;
    float bvj[4];
#pragma unroll
    for (int j = 0; j < 4; ++j) bvj[j] = bias[tile_n + cw + j * 16 + lrow];
    float cs[4] = {0.f, 0.f, 0.f, 0.f}, cq[4] = {0.f, 0.f, 0.f, 0.f};

#pragma unroll
    for (int i = 0; i < 4; ++i) {
#pragma unroll
        for (int j = 0; j < 4; ++j) {
#pragma unroll
            for (int r = 0; r < 4; ++r) {
                int row = tile_m + rw + i * 16 + quad * 4 + r;
                float v = acc[i][j][r] + bvj[j];
                if (row < M) { cs[j] += v; cq[j] += v * v; }
                slice[(quad * 4 + r) * 64 + ((j ^ quad) * 16) + lrow] = f2bf(v);
            }
        }
        __syncthreads();
        // readback: 128 uint4 chunks (16 rows x 8 chunks), lane handles 2
#pragma unroll
        for (int c = 0; c < 2; ++c) {
            int ch = lane + c * 64;
            int lr = ch >> 3, sg = ch & 7;
            int grow = tile_m + rw + i * 16 + lr;
            if (grow < M) {
                const bf16* srcp = slice + lr * 64 + (((sg >> 1) ^ (lr >> 2)) << 4) + ((sg & 1) << 3);
                uint4 v = *(const uint4*)srcp;
                *(uint4*)(C + (size_t)grow * HID + tile_n + cw + sg * 8) = v;
            }
        }
        __syncthreads();
    }

    // reduce across the 4 quads that share each (j,lrow) column
#pragma unroll
    for (int j = 0; j < 4; ++j) {
        cs[j] += __shfl_xor(cs[j], 16, 64); cs[j] += __shfl_xor(cs[j], 32, 64);
        cq[j] += __shfl_xor(cq[j], 16, 64); cq[j] += __shfl_xor(cq[j], 32, 64);
    }
    if (quad == 0) {
#pragma unroll
        for (int j = 0; j < 4; ++j) {
            sred[wave][j * 16 + lrow] = cs[j];
            qred[wave][j * 16 + lrow] = cq[j];
        }
    }
    __syncthreads();
    int bid = blockIdx.y * gridDim.x + blockIdx.x;
    if (tid < 128) {
        int grp = tid >> 6, idx = tid & 63;
        psum[(size_t)bid * 128 + tid] = sred[grp][idx] + sred[grp + 2][idx];
    } else {
        int t = tid - 128;
        int grp = t >> 6, idx = t & 63;
        psq[(size_t)bid * 128 + t] = qred[grp][idx] + qred[grp + 2][idx];
    }
}

// reduce per-block partials -> stats[0..255]=sum, stats[256..511]=sumsq
__global__ void bn_finalize_kernel(const float* __restrict__ psum, const float* __restrict__ psq,
                                   float* __restrict__ stats, int nby) {
    const float* src = blockIdx.y ? psq : psum;
    int c = threadIdx.x;           // 0..255 = global column
    int bx = c >> 7, cl = c & 127;
    int per = (nby + gridDim.x - 1) / gridDim.x;
    int b0 = blockIdx.x * per, b1 = min(b0 + per, nby);
    float s = 0.f;
    for (int by = b0; by < b1; ++by) s += src[(size_t)(by * 2 + bx) * 128 + cl];
    atomicAdd(&stats[blockIdx.y * HID + c], s);
}

// ---------------- BN apply + ReLU (layer 1; also emits fp8 copy for gather) ----------------

__global__ void bn_apply_relu_kernel(bf16* __restrict__ h, unsigned char* __restrict__ hf8,
                                     const float* __restrict__ stats,
                                     const float* __restrict__ g, const float* __restrict__ be,
                                     int M) {
    int i4 = blockIdx.x * blockDim.x + threadIdx.x;
    int total4 = M * (HID / 4);
    if (i4 >= total4) return;
    int col4 = i4 & (HID / 4 - 1);
    ushort4 v = ((const ushort4*)h)[i4];
    float invN = 1.0f / (float)M;
    float o[4] = {bf2f(v.x), bf2f(v.y), bf2f(v.z), bf2f(v.w)};
#pragma unroll
    for (int j = 0; j < 4; ++j) {
        int col = col4 * 4 + j;
        float mu = stats[col] * invN;
        float var = stats[HID + col] * invN - mu * mu;
        float sc = rsqrtf(var + BN_EPS) * g[col];
        float val = (o[j] - mu) * sc + be[col];
        o[j] = val > 0.f ? val : 0.f;
    }
    ushort4 r;
    r.x = f2bf(o[0]); r.y = f2bf(o[1]); r.z = f2bf(o[2]); r.w = f2bf(o[3]);
    ((ushort4*)h)[i4] = r;
    ((unsigned int*)hf8)[i4] = pack4_fp8(o[0], o[1], o[2], o[3]);
}

// ---------------- final FC (MFMA) with fused BN2+ReLU ----------------

#define BSTR 264   // 256 + 8 pad

__global__ __launch_bounds__(256) void fc_bn_mfma_kernel(
    const bf16* __restrict__ h, const float* __restrict__ stats,
    const float* __restrict__ g, const float* __restrict__ be,
    const bf16* __restrict__ WfcT, const float* __restrict__ bfc,
    float* __restrict__ out, int M) {
    __shared__ bf16 Bs[32 * BSTR];
    __shared__ float sc_s[HID], sh_s[HID];
    int tid = threadIdx.x;
    for (int i = tid; i < 32 * 32; i += 256) {   // 1024 16B chunks
        int rrow = i >> 5, seg = i & 31;
        *(uint4*)(Bs + rrow * BSTR + seg * 8) = *(const uint4*)(WfcT + (size_t)rrow * HID + seg * 8);
    }
    {
        float invN = 1.0f / (float)M;
        float mu = stats[tid] * invN;
        float var = stats[HID + tid] * invN - mu * mu;
        float s = rsqrtf(var + BN_EPS) * g[tid];
        sc_s[tid] = s;
        sh_s[tid] = be[tid] - mu * s;
    }
    __syncthreads();
    int wave = tid >> 6, lane = tid & 63, lrow = lane & 15, quad = lane >> 4;
    int row = blockIdx.x * 64 + wave * 16 + lrow;
    const bf16* hrow = h + (size_t)row * HID;
    float4v acc0 = {0.f, 0.f, 0.f, 0.f}, acc1 = {0.f, 0.f, 0.f, 0.f};
#pragma unroll
    for (int ks = 0; ks < 8; ++ks) {
        int k0 = ks * 32 + quad * 8;
        uint4 av = {0u, 0u, 0u, 0u};
        if (row < M) av = *(const uint4*)(hrow + k0);
        union { unsigned int u[4]; short8 s8; } cvt;
        unsigned int* avp = (unsigned int*)&av;
#pragma unroll
        for (int t = 0; t < 4; ++t) {
            int k = k0 + t * 2;
            float v0 = blo(avp[t]) * sc_s[k] + sh_s[k];
            float v1 = bhi(avp[t]) * sc_s[k + 1] + sh_s[k + 1];
            v0 = v0 > 0.f ? v0 : 0.f;
            v1 = v1 > 0.f ? v1 : 0.f;
            cvt.u[t] = pack2(v0, v1);
        }
        short8 b0 = *(const short8*)(Bs + lrow * BSTR + k0);
        short8 b1 = *(const short8*)(Bs + (16 + lrow) * BSTR + k0);
        acc0 = __builtin_amdgcn_mfma_f32_16x16x32_bf16(cvt.s8, b0, acc0, 0, 0, 0);
        acc1 = __builtin_amdgcn_mfma_f32_16x16x32_bf16(cvt.s8, b1, acc1, 0, 0, 0);
    }
    int orow = blockIdx.x * 64 + wave * 16 + quad * 4;
    float bv0 = bfc[lrow], bv1 = bfc[16 + lrow];
#pragma unroll
    for (int r = 0; r < 4; ++r) {
        int rr = orow + r;
        if (rr < M) {
            out[(size_t)rr * N_CLS + lrow] = acc0[r] + bv0;
            out[(size_t)rr * N_CLS + 16 + lrow] = acc1[r] + bv1;
        }
    }
}

// ---------------- launch ----------------

extern "C" void kernel_launch(void* const* d_in, const int* in_sizes, int n_in,
                              void* d_out, int out_size, void* d_ws, size_t ws_size,
                              hipStream_t stream) {
    const float* x   = (const float*)d_in[0];
    const int* esrc  = (const int*)d_in[1];
    const int* edst  = (const int*)d_in[2];
    const float* W1l = (const float*)d_in[3];
    const float* b1  = (const float*)d_in[4];
    const float* W1r = (const float*)d_in[5];
    const float* g1  = (const float*)d_in[6];
    const float* be1 = (const float*)d_in[7];
    const float* W2l = (const float*)d_in[8];
    const float* b2  = (const float*)d_in[9];
    const float* W2r = (const float*)d_in[10];
    const float* g2  = (const float*)d_in[11];
    const float* be2 = (const float*)d_in[12];
    const float* Wfc = (const float*)d_in[13];
    const float* bfc = (const float*)d_in[14];
    float* out = (float*)d_out;

    char* ws = (char*)d_ws;
    size_t o = 0;
    auto carve = [&](size_t bytes) {
        char* p = ws + o;
        o = (o + bytes + 255) & ~(size_t)255;
        return p;
    };
    int*   off    = (int*)carve((N_NODES + 1) * sizeof(int));
    int*   cursor = (int*)carve(N_NODES * sizeof(int));
    int*   csr    = (int*)carve(N_EDGES * sizeof(int));
    int*   bsums  = (int*)carve(SCAN_NB * sizeof(int));
    int*   boffs  = (int*)carve(SCAN_NB * sizeof(int));
    int*   bcur   = (int*)carve(NBUCK * sizeof(int));
    float* stats1 = (float*)carve(2 * HID * sizeof(float));
    float* stats2 = (float*)carve(2 * HID * sizeof(float));
    float* psum   = (float*)carve((size_t)GEMM_NB * 128 * sizeof(float));
    float* psq    = (float*)carve((size_t)GEMM_NB * 128 * sizeof(float));
    bf16*  w1lt   = (bf16*)carve((size_t)IN_DIM * HID * sizeof(bf16));
    bf16*  w1rt   = (bf16*)carve((size_t)IN_DIM * HID * sizeof(bf16));
    bf16*  w2lt   = (bf16*)carve((size_t)HID * HID * sizeof(bf16));
    bf16*  w2rt   = (bf16*)carve((size_t)HID * HID * sizeof(bf16));
    bf16*  wfct   = (bf16*)carve((size_t)N_CLS * HID * sizeof(bf16));
    bf16*  agg    = (bf16*)carve((size_t)N_NODES * HID * sizeof(bf16));
    bf16*  h1     = (bf16*)carve((size_t)N_NODES * HID * sizeof(bf16));
    bf16*  h2     = (bf16*)carve((size_t)N_NODES * HID * sizeof(bf16));
    // overlays inside the h2 region (lifetimes stream-ordered disjoint):
    //   xb  = h2[0   : 25.6MB]  bf16 x   — dead after gemm1
    //   xf8 = h2[25.6: 38.4MB]  fp8 x    — dead after aggregate1
    //   h1f8= h2[0   : 25.6MB]  fp8 bn(h1) — written post-gemm1, read by aggregate2,
    //                                        then gemm2 overwrites h2
    bf16*          xb   = h2;
    unsigned char* xf8  = (unsigned char*)h2 + (size_t)N_NODES * IN_DIM * sizeof(bf16);
    unsigned char* h1f8 = (unsigned char*)h2;
    // overlay inside the agg region (dead until aggregate1 writes it):
    //   bstore = 16 buckets x 112K edges x 8B = 14.3 MB < 51.2 MB
    int2*          bstore = (int2*)agg;
    // overlay inside the h1 region (dead until gemm1 writes it):
    //   partial = HSUBS x N_NODES ints = 12.8 MB < 51.2 MB
    int*           partial = (int*)h1;

    if (o > ws_size) return;  // clean fail instead of fault

    hipMemsetAsync(bcur, 0, NBUCK * sizeof(int), stream);
    hipMemsetAsync(stats1, 0, 2 * HID * sizeof(float), stream);
    hipMemsetAsync(stats2, 0, 2 * HID * sizeof(float), stream);

    // CSR build: bucket scatter -> LDS-privatized degree hist -> scans (scan1 also
    // produces the per-slice exclusive prefix) -> deterministic per-bucket fill.
    // Zero per-edge global atomics anywhere.
    bucket_scatter_kernel<<<PASSA_NB, 256, 0, stream>>>(esrc, edst, bcur, bstore);
    bucket_hist_kernel<<<NBUCK * HSUBS, 256, 0, stream>>>(bstore, bcur, partial);
    scan1_kernel<<<SCAN_NB, 256, 0, stream>>>(partial, cursor, bsums);   // cursor <- counts
    scan2_kernel<<<1, 128, 0, stream>>>(bsums, boffs);
    scan3_kernel<<<SCAN_NB, 256, 0, stream>>>(cursor, boffs, off);
    fill_bucket_kernel<<<NBUCK * HSUBS, 256, 0, stream>>>(bstore, bcur, off, partial, csr);

    // prep: x -> bf16 + fp8, all weights -> bf16 transposed
    convert_x_kernel<<<(N_NODES * IN_DIM / 4 + 255) / 256, 256, 0, stream>>>(x, xb, xf8);
    {
        int total = 2 * IN_DIM * HID + 2 * HID * HID + HID * N_CLS;
        prep_weights_kernel<<<(total + 255) / 256, 256, 0, stream>>>(
            W1l, W1r, W2l, W2r, Wfc, w1lt, w1rt, w2lt, w2rt, wfct);
    }

    const dim3 ggrid(HID / 128, GEMM_NBY);

    // ---- layer 1 ----
    aggregate1_kernel<<<(N_NODES * 8 + 255) / 256, 256, 0, stream>>>(xf8, off, csr, agg);
    gemm_dual_mfma<<<ggrid, 256, 0, stream>>>(
        agg, w1lt, IN_DIM, xb, w1rt, IN_DIM, b1, h1, N_NODES, psum, psq);
    bn_finalize_kernel<<<dim3(8, 2), 256, 0, stream>>>(psum, psq, stats1, GEMM_NBY);
    {
        int total4 = N_NODES * (HID / 4);
        bn_apply_relu_kernel<<<(total4 + 255) / 256, 256, 0, stream>>>(h1, h1f8, stats1, g1, be1, N_NODES);
    }

    // ---- layer 2 ----
    aggregate2_kernel<<<(N_NODES * 16 + 255) / 256, 256, 0, stream>>>(h1f8, off, csr, agg);
    gemm_dual_mfma<<<ggrid, 256, 0, stream>>>(
        agg, w2lt, HID, h1, w2rt, HID, b2, h2, N_NODES, psum, psq);
    bn_finalize_kernel<<<dim3(8, 2), 256, 0, stream>>>(psum, psq, stats2, GEMM_NBY);

    // ---- final FC (MFMA) with fused BN2+ReLU ----
    fc_bn_mfma_kernel<<<(N_NODES + 63) / 64, 256, 0, stream>>>(
        h2, stats2, g2, be2, wfct, bfc, out, N_NODES);
}